// Round 1
// baseline (989.839 us; speedup 1.0000x reference)
//
#include <hip/hip_runtime.h>
#include <math.h>

#define T_SEQ 1024
#define NSH   16
#define HTOT  64
#define DH    64
#define LOG2_10000 13.287712379549449f

// ------------------------------------------------------------------
// GEMM: C[MxN] = A[MxK] @ B[KxN] + bias[N]   (row-major everything)
// 128x128 block tile, BK=16, 256 threads, 8x8 micro-tile per thread.
// A staged transposed As[kk][m]; B rows read strided (tx + 16j) ->
// conflict-free scalar LDS reads; A read as float4 (banks 0/8/16/24).
// ------------------------------------------------------------------
__global__ __launch_bounds__(256) void gemm_bias_kernel(
    const float* __restrict__ A, const float* __restrict__ Bw,
    const float* __restrict__ bias, float* __restrict__ Cout,
    int M, int N, int K)
{
  __shared__ __align__(16) float As[16][132];
  __shared__ __align__(16) float Bs[16][132];
  const int tid = threadIdx.x;
  const int n0 = blockIdx.x * 128;
  const int m0 = blockIdx.y * 128;
  const int tx = tid & 15;
  const int ty = tid >> 4;

  float acc[8][8];
#pragma unroll
  for (int i = 0; i < 8; ++i)
#pragma unroll
    for (int j = 0; j < 8; ++j) acc[i][j] = 0.f;

  for (int k0 = 0; k0 < K; k0 += 16) {
    __syncthreads();
#pragma unroll
    for (int q = 0; q < 2; ++q) {
      int f = tid + 256 * q;           // 0..511
      int r  = f >> 2, c4 = f & 3;     // A tile: 128 rows x 4 f4-cols
      const float4 av = *reinterpret_cast<const float4*>(
          &A[(size_t)(m0 + r) * K + k0 + c4 * 4]);
      As[c4 * 4 + 0][r] = av.x;
      As[c4 * 4 + 1][r] = av.y;
      As[c4 * 4 + 2][r] = av.z;
      As[c4 * 4 + 3][r] = av.w;
      int kk = f >> 5, cb = f & 31;    // B tile: 16 rows x 32 f4-cols
      *reinterpret_cast<float4*>(&Bs[kk][cb * 4]) =
          *reinterpret_cast<const float4*>(&Bw[(size_t)(k0 + kk) * N + n0 + cb * 4]);
    }
    __syncthreads();
#pragma unroll
    for (int kk = 0; kk < 16; ++kk) {
      float4 a0 = *reinterpret_cast<const float4*>(&As[kk][ty * 8]);
      float4 a1 = *reinterpret_cast<const float4*>(&As[kk][ty * 8 + 4]);
      float av[8] = {a0.x, a0.y, a0.z, a0.w, a1.x, a1.y, a1.z, a1.w};
      float bv[8];
#pragma unroll
      for (int j = 0; j < 8; ++j) bv[j] = Bs[kk][tx + 16 * j];
#pragma unroll
      for (int i = 0; i < 8; ++i)
#pragma unroll
        for (int j = 0; j < 8; ++j) acc[i][j] = fmaf(av[i], bv[j], acc[i][j]);
    }
  }
#pragma unroll
  for (int i = 0; i < 8; ++i) {
    int row = m0 + ty * 8 + i;
#pragma unroll
    for (int j = 0; j < 8; ++j) {
      int col = n0 + tx + 16 * j;
      Cout[(size_t)row * N + col] = acc[i][j] + bias[col];
    }
  }
}

__device__ __forceinline__ float wave_sum64(float v) {
  v += __shfl_xor(v, 1, 64);
  v += __shfl_xor(v, 2, 64);
  v += __shfl_xor(v, 4, 64);
  v += __shfl_xor(v, 8, 64);
  v += __shfl_xor(v, 16, 64);
  v += __shfl_xor(v, 32, 64);
  return v;
}

// rms_norm + rope, in place on Qp[(b*T+t)*4096 + h*64 + d]; one wave per row
__global__ __launch_bounds__(256) void q_transform_kernel(float* __restrict__ Qp) {
  int wid  = blockIdx.x * 4 + (threadIdx.x >> 6);  // row id: bt*64 + h
  int lane = threadIdx.x & 63;
  int h  = wid & 63;
  int bt = wid >> 6;
  int t  = bt & (T_SEQ - 1);
  float* row = Qp + (size_t)bt * 4096 + h * 64;
  float x  = row[lane];
  float ss = wave_sum64(x * x);
  float xn = x * rsqrtf(ss * (1.0f / 64.0f) + 1.1920929e-7f);  // eps = finfo(f32).eps
  int p = lane & 31;
  float x1 = __shfl(xn, 2 * p, 64);
  float x2 = __shfl(xn, 2 * p + 1, 64);
  float invf = exp2f(-LOG2_10000 * (float)(2 * p) * (1.0f / 64.0f));
  float ang = (float)t * invf;
  float sn, cs;
  sincosf(ang, &sn, &cs);
  row[lane] = (lane < 32) ? (x1 * cs - x2 * sn) : (x1 * sn + x2 * cs);
}

// rope + unit-normalize (folds ||k|| denominator), in place on Kp
__global__ __launch_bounds__(256) void k_transform_kernel(float* __restrict__ Kp) {
  int wid  = blockIdx.x * 4 + (threadIdx.x >> 6);  // row id: bt*16 + hs
  int lane = threadIdx.x & 63;
  int hs = wid & 15;
  int bt = wid >> 4;
  int t  = bt & (T_SEQ - 1);
  float* row = Kp + (size_t)bt * 1024 + hs * 64;
  float x = row[lane];
  int p = lane & 31;
  float x1 = __shfl(x, 2 * p, 64);
  float x2 = __shfl(x, 2 * p + 1, 64);
  float invf = exp2f(-LOG2_10000 * (float)(2 * p) * (1.0f / 64.0f));
  float ang = (float)t * invf;
  float sn, cs;
  sincosf(ang, &sn, &cs);
  float xr = (lane < 32) ? (x1 * cs - x2 * sn) : (x1 * sn + x2 * cs);
  float ss = wave_sum64(xr * xr);   // rotation preserves norm; compute post-rope
  row[lane] = xr * rsqrtf(ss);
}

// Vsum[b][h][d] = sum_t Vp[(b*T+t)*4096 + h*64 + d]
__global__ void vsum_kernel(const float* __restrict__ Vp, float* __restrict__ Vsum) {
  int bh = blockIdx.x;   // b*64 + h
  int d  = threadIdx.x;  // 0..63
  int b = bh >> 6, h = bh & 63;
  float s = 0.f;
  for (int tt = 0; tt < T_SEQ; ++tt)
    s += Vp[(size_t)(b * T_SEQ + tt) * 4096 + h * 64 + d];
  Vsum[bh * 64 + d] = s;
}

// ------------------------------------------------------------------
// Banded attention with logit-0 masking handled algebraically:
//   num_d = S_all[d] + sum_band (e^w - 1) v_d + es * vnull_d
//   Z     = T + sum_band (e^w - 1) + es,   es = exp(tanh(sink))
// Block = (b, hs, 32-query tile); loops 4 branches; writes
// mctx = 0.25 * sum_br out_br directly (mean folded before WO GEMM).
// ------------------------------------------------------------------
__global__ __launch_bounds__(256) void attn_kernel(
    const float* __restrict__ Qp,    // [B*T][4096]  roped+rms q
    const float* __restrict__ Khat,  // [B*T][1024]  roped unit k
    const float* __restrict__ Vp,    // [B*T][4096]
    const float* __restrict__ Vsum,  // [B*64][64]
    const float* __restrict__ sink,  // [64]
    const float* __restrict__ vnull, // [64][64]
    float* __restrict__ mctx)        // [B*T][1024]
{
  __shared__ __align__(16) float qs[32][68];
  __shared__ __align__(16) float ks[64][68];
  __shared__ __align__(16) float vs[64][68];
  __shared__ __align__(16) float pe[32][64];

  const int tid = threadIdx.x;
  const int blk = blockIdx.x;      // b*512 + hs*32 + qt
  const int qt  = blk & 31;
  const int hs  = (blk >> 5) & 15;
  const int b   = blk >> 9;
  const int qt0 = qt * 32;
  const int qi  = tid >> 3;        // 0..31 query row
  const int u   = tid & 7;         // 0..7
  const int t   = qt0 + qi;

  const int HCFG[4] = {16, 128, 128, 512};
  const int GCFG[4] = {0, 16, 0, 144};

  float macc[8];
#pragma unroll
  for (int i = 0; i < 8; ++i) macc[i] = 0.f;

  for (int br = 0; br < 4; ++br) {
    const int h = br * 16 + hs;
    const int hmax = HCFG[br], g = GCFG[br];

    __syncthreads();  // protect qs from previous branch readers
#pragma unroll
    for (int q4 = 0; q4 < 2; ++q4) {   // stage 32x64 q tile
      int f = tid + 256 * q4;
      int r = f >> 4, c4 = f & 15;
      *reinterpret_cast<float4*>(&qs[r][c4 * 4]) =
          *reinterpret_cast<const float4*>(
              &Qp[(size_t)(b * T_SEQ + qt0 + r) * 4096 + h * 64 + c4 * 4]);
    }
    float outv[8];
#pragma unroll
    for (int i = 0; i < 8; ++i) outv[i] = 0.f;
    float zpart = 0.f;
    __syncthreads();

    int klo = qt0 - (hmax - 1); if (klo < 0) klo = 0;
    int khi = qt0 + 31 - g;     if (khi > T_SEQ - 1) khi = T_SEQ - 1;

    for (int j0 = klo; j0 <= khi; j0 += 64) {
      __syncthreads();  // protect ks/vs/pe from previous chunk readers
#pragma unroll
      for (int q4 = 0; q4 < 4; ++q4) {  // stage 64x64 k-hat and v tiles
        int f = tid + 256 * q4;
        int r = f >> 4, c4 = f & 15;
        int j = j0 + r;
        float4 kv = make_float4(0.f, 0.f, 0.f, 0.f);
        float4 vv = make_float4(0.f, 0.f, 0.f, 0.f);
        if (j < T_SEQ) {
          kv = *reinterpret_cast<const float4*>(
              &Khat[(size_t)(b * T_SEQ + j) * 1024 + hs * 64 + c4 * 4]);
          vv = *reinterpret_cast<const float4*>(
              &Vp[(size_t)(b * T_SEQ + j) * 4096 + h * 64 + c4 * 4]);
        }
        *reinterpret_cast<float4*>(&ks[r][c4 * 4]) = kv;
        *reinterpret_cast<float4*>(&vs[r][c4 * 4]) = vv;
      }
      __syncthreads();

      // scores: thread (qi,u) handles keys jj = u + 8w (stride-8 -> no bank conflict)
      float s[8];
#pragma unroll
      for (int w = 0; w < 8; ++w) s[w] = 0.f;
#pragma unroll
      for (int d4 = 0; d4 < 16; ++d4) {
        float4 qv = *reinterpret_cast<const float4*>(&qs[qi][d4 * 4]);
#pragma unroll
        for (int w = 0; w < 8; ++w) {
          float4 kv = *reinterpret_cast<const float4*>(&ks[u + 8 * w][d4 * 4]);
          s[w] += qv.x * kv.x + qv.y * kv.y + qv.z * kv.z + qv.w * kv.w;
        }
      }
#pragma unroll
      for (int w = 0; w < 8; ++w) {
        int jj = u + 8 * w;
        int j = j0 + jj;
        int dist = t - j;
        bool inband = (dist >= g) && (dist < hmax) && (j < T_SEQ);
        float val = inband ? (expf(s[w]) - 1.0f) : 0.f;
        pe[qi][jj] = val;
        zpart += val;
      }
      __syncthreads();

      // PV: thread (qi,u) accumulates d = u*8 .. u*8+7
#pragma unroll 4
      for (int jj4 = 0; jj4 < 16; ++jj4) {
        float4 pw = *reinterpret_cast<const float4*>(&pe[qi][jj4 * 4]);
        if (pw.x == 0.f && pw.y == 0.f && pw.z == 0.f && pw.w == 0.f) continue;
        float pwa[4] = {pw.x, pw.y, pw.z, pw.w};
#pragma unroll
        for (int e = 0; e < 4; ++e) {
          int jj = jj4 * 4 + e;
          float4 v0 = *reinterpret_cast<const float4*>(&vs[jj][u * 8]);
          float4 v1 = *reinterpret_cast<const float4*>(&vs[jj][u * 8 + 4]);
          float wv = pwa[e];
          outv[0] = fmaf(wv, v0.x, outv[0]);
          outv[1] = fmaf(wv, v0.y, outv[1]);
          outv[2] = fmaf(wv, v0.z, outv[2]);
          outv[3] = fmaf(wv, v0.w, outv[3]);
          outv[4] = fmaf(wv, v1.x, outv[4]);
          outv[5] = fmaf(wv, v1.y, outv[5]);
          outv[6] = fmaf(wv, v1.z, outv[6]);
          outv[7] = fmaf(wv, v1.w, outv[7]);
        }
      }
    }

    // reduce z over the 8 threads sharing qi (low 3 lane bits)
    float z = zpart;
    z += __shfl_xor(z, 1, 64);
    z += __shfl_xor(z, 2, 64);
    z += __shfl_xor(z, 4, 64);
    float es = expf(tanhf(sink[h]));
    float invZ = 1.0f / ((float)T_SEQ + z + es);
#pragma unroll
    for (int i = 0; i < 8; ++i) {
      int d = u * 8 + i;
      float num = outv[i] + Vsum[(b * 64 + h) * 64 + d] + es * vnull[h * 64 + d];
      macc[i] += num * invZ;
    }
  }

#pragma unroll
  for (int i = 0; i < 8; ++i) {
    int d = u * 8 + i;
    mctx[(size_t)(b * T_SEQ + t) * 1024 + hs * 64 + d] = 0.25f * macc[i];
  }
}

extern "C" void kernel_launch(void* const* d_in, const int* in_sizes, int n_in,
                              void* d_out, int out_size, void* d_ws, size_t ws_size,
                              hipStream_t stream) {
  (void)in_sizes; (void)n_in; (void)out_size; (void)ws_size;
  const float* X    = (const float*)d_in[0];
  const float* WQ   = (const float*)d_in[1];
  const float* bQ   = (const float*)d_in[2];
  const float* WK   = (const float*)d_in[3];
  const float* bK   = (const float*)d_in[4];
  const float* WV   = (const float*)d_in[5];
  const float* bV   = (const float*)d_in[6];
  const float* WO   = (const float*)d_in[7];
  const float* bO   = (const float*)d_in[8];
  const float* sink = (const float*)d_in[9];
  const float* vnul = (const float*)d_in[10];
  float* Y = (float*)d_out;

  float* Qp   = (float*)d_ws;                       // 2048*4096
  float* Vp   = Qp   + (size_t)2048 * 4096;         // 2048*4096
  float* Kp   = Vp   + (size_t)2048 * 4096;         // 2048*1024
  float* mctx = Kp   + (size_t)2048 * 1024;         // 2048*1024
  float* Vsum = mctx + (size_t)2048 * 1024;         // 128*64
  // total ws use: ~84 MB

  dim3 blk(256);
  gemm_bias_kernel<<<dim3(4096 / 128, 2048 / 128), blk, 0, stream>>>(X, WQ, bQ, Qp, 2048, 4096, 1024);
  gemm_bias_kernel<<<dim3(1024 / 128, 2048 / 128), blk, 0, stream>>>(X, WK, bK, Kp, 2048, 1024, 1024);
  gemm_bias_kernel<<<dim3(4096 / 128, 2048 / 128), blk, 0, stream>>>(X, WV, bV, Vp, 2048, 4096, 1024);
  q_transform_kernel<<<(2048 * 64) / 4, 256, 0, stream>>>(Qp);
  k_transform_kernel<<<(2048 * 16) / 4, 256, 0, stream>>>(Kp);
  vsum_kernel<<<128, 64, 0, stream>>>(Vp, Vsum);
  attn_kernel<<<2 * 16 * 32, 256, 0, stream>>>(Qp, Kp, Vp, Vsum, sink, vnul, mctx);
  gemm_bias_kernel<<<dim3(1024 / 128, 2048 / 128), blk, 0, stream>>>(mctx, WO, bO, Y, 2048, 1024, 1024);
}

// Round 2
// 410.587 us; speedup vs baseline: 2.4108x; 2.4108x over previous
//
#include <hip/hip_runtime.h>
#include <hip/hip_bf16.h>
#include <math.h>

#define T_SEQ 1024
#define LOG2_10000 13.287712379549449f

typedef unsigned short u16;
typedef __attribute__((ext_vector_type(8))) short bf16x8;
typedef __attribute__((ext_vector_type(4))) float f32x4;

// ------------------------------------------------------------------
// async global->LDS, 16B per lane (global_load_lds_dwordx4)
// ------------------------------------------------------------------
__device__ __forceinline__ void gload16(const u16* g, u16* s) {
  __builtin_amdgcn_global_load_lds(
      (const __attribute__((address_space(1))) void*)g,
      (__attribute__((address_space(3))) void*)s, 16, 0, 0);
}

// ------------------------------------------------------------------
// fp32 -> bf16 elementwise (8 elems / thread)
// ------------------------------------------------------------------
__global__ __launch_bounds__(256) void cvt_bf16_kernel(
    const float* __restrict__ in, u16* __restrict__ out, int n8) {
  int i = blockIdx.x * 256 + threadIdx.x;
  if (i >= n8) return;
  float4 a = reinterpret_cast<const float4*>(in)[2 * i];
  float4 b = reinterpret_cast<const float4*>(in)[2 * i + 1];
  __hip_bfloat16 o[8] = {
      __float2bfloat16(a.x), __float2bfloat16(a.y),
      __float2bfloat16(a.z), __float2bfloat16(a.w),
      __float2bfloat16(b.x), __float2bfloat16(b.y),
      __float2bfloat16(b.z), __float2bfloat16(b.w)};
  reinterpret_cast<uint4*>(out)[i] = *reinterpret_cast<const uint4*>(o);
}

// ------------------------------------------------------------------
// W[K][N] fp32 -> Wt[N][K] bf16 (32x32 LDS tile transpose)
// ------------------------------------------------------------------
__global__ __launch_bounds__(256) void transpose_cvt_kernel(
    const float* __restrict__ W, u16* __restrict__ Wt, int N, int K) {
  __shared__ float tile[32][33];
  int n0 = blockIdx.x * 32, k0 = blockIdx.y * 32;
  int t = threadIdx.x;
  int r = t >> 3, c4 = (t & 7) * 4;
  float4 v = *reinterpret_cast<const float4*>(&W[(size_t)(k0 + r) * N + n0 + c4]);
  tile[r][c4 + 0] = v.x;
  tile[r][c4 + 1] = v.y;
  tile[r][c4 + 2] = v.z;
  tile[r][c4 + 3] = v.w;
  __syncthreads();
  __hip_bfloat16 o[4];
#pragma unroll
  for (int i = 0; i < 4; ++i) o[i] = __float2bfloat16(tile[c4 + i][r]);
  *reinterpret_cast<uint2*>(&Wt[(size_t)(n0 + r) * K + k0 + c4]) =
      *reinterpret_cast<const uint2*>(o);
}

// ------------------------------------------------------------------
// bf16 MFMA GEMM (m97 structure): C[MxN] = A[MxK] @ Bt[NxK]^T + bias
// 128x128 tile, BK=32, 256 threads = 4 waves (2x2), 4x4 frags/wave.
// ------------------------------------------------------------------
__global__ __launch_bounds__(256) void gemm_bf16_kernel(
    const u16* __restrict__ Ab, const u16* __restrict__ Bt,
    const float* __restrict__ bias, float* __restrict__ C,
    int M, int N, int K)
{
  __shared__ __align__(16) u16 sA[128 * 32];
  __shared__ __align__(16) u16 sB[128 * 32];
  const int tid = threadIdx.x;
  const int lane = tid & 63;
  const int wv = tid >> 6;
  const int wm = wv >> 1, wn = wv & 1;
  const int m0 = blockIdx.y * 128, n0 = blockIdx.x * 128;

  f32x4 acc[4][4];
#pragma unroll
  for (int i = 0; i < 4; ++i)
#pragma unroll
    for (int j = 0; j < 4; ++j) acc[i][j] = (f32x4){0.f, 0.f, 0.f, 0.f};

  // staging: flat 16B-chunk index f = q*256 + tid; row = f>>2, kchunk = f&3
  const int r0 = tid >> 2, kc = tid & 3;
  const u16* a_src0 = Ab + (size_t)(m0 + r0) * K + kc * 8;
  const u16* a_src1 = Ab + (size_t)(m0 + 64 + r0) * K + kc * 8;
  const u16* b_src0 = Bt + (size_t)(n0 + r0) * K + kc * 8;
  const u16* b_src1 = Bt + (size_t)(n0 + 64 + r0) * K + kc * 8;
  u16* sA0 = sA + (size_t)(wv * 64) * 8;
  u16* sA1 = sA + (size_t)(256 + wv * 64) * 8;
  u16* sB0 = sB + (size_t)(wv * 64) * 8;
  u16* sB1 = sB + (size_t)(256 + wv * 64) * 8;

  const int arow = wm * 64 + (lane & 15);
  const int brow = wn * 64 + (lane & 15);
  const int kcol = (lane >> 4) * 8;

  for (int k0 = 0; k0 < K; k0 += 32) {
    __syncthreads();
    gload16(a_src0 + k0, sA0);
    gload16(a_src1 + k0, sA1);
    gload16(b_src0 + k0, sB0);
    gload16(b_src1 + k0, sB1);
    __syncthreads();
    bf16x8 af[4], bfv[4];
#pragma unroll
    for (int mi = 0; mi < 4; ++mi)
      af[mi] = *reinterpret_cast<const bf16x8*>(&sA[(arow + mi * 16) * 32 + kcol]);
#pragma unroll
    for (int ni = 0; ni < 4; ++ni)
      bfv[ni] = *reinterpret_cast<const bf16x8*>(&sB[(brow + ni * 16) * 32 + kcol]);
#pragma unroll
    for (int mi = 0; mi < 4; ++mi)
#pragma unroll
      for (int ni = 0; ni < 4; ++ni)
        acc[mi][ni] = __builtin_amdgcn_mfma_f32_16x16x32_bf16(
            af[mi], bfv[ni], acc[mi][ni], 0, 0, 0);
  }

  // C/D layout: col = lane&15, row = (lane>>4)*4 + reg
  const int crow = m0 + wm * 64 + (lane >> 4) * 4;
  const int ccol = n0 + wn * 64 + (lane & 15);
#pragma unroll
  for (int mi = 0; mi < 4; ++mi)
#pragma unroll
    for (int ni = 0; ni < 4; ++ni) {
      int col = ccol + ni * 16;
      float bv = bias[col];
#pragma unroll
      for (int r = 0; r < 4; ++r)
        C[(size_t)(crow + mi * 16 + r) * N + col] = acc[mi][ni][r] + bv;
    }
}

__device__ __forceinline__ float wave_sum64(float v) {
  v += __shfl_xor(v, 1, 64);
  v += __shfl_xor(v, 2, 64);
  v += __shfl_xor(v, 4, 64);
  v += __shfl_xor(v, 8, 64);
  v += __shfl_xor(v, 16, 64);
  v += __shfl_xor(v, 32, 64);
  return v;
}

// rms_norm + rope, in place on Qp[(b*T+t)*4096 + h*64 + d]; one wave per row
__global__ __launch_bounds__(256) void q_transform_kernel(float* __restrict__ Qp) {
  int wid  = blockIdx.x * 4 + (threadIdx.x >> 6);
  int lane = threadIdx.x & 63;
  int h  = wid & 63;
  int bt = wid >> 6;
  int t  = bt & (T_SEQ - 1);
  float* row = Qp + (size_t)bt * 4096 + h * 64;
  float x  = row[lane];
  float ss = wave_sum64(x * x);
  float xn = x * rsqrtf(ss * (1.0f / 64.0f) + 1.1920929e-7f);
  int p = lane & 31;
  float x1 = __shfl(xn, 2 * p, 64);
  float x2 = __shfl(xn, 2 * p + 1, 64);
  float invf = exp2f(-LOG2_10000 * (float)(2 * p) * (1.0f / 64.0f));
  float ang = (float)t * invf;
  float sn, cs;
  sincosf(ang, &sn, &cs);
  row[lane] = (lane < 32) ? (x1 * cs - x2 * sn) : (x1 * sn + x2 * cs);
}

// rope + unit-normalize (folds ||k|| denominator), in place on Kp
__global__ __launch_bounds__(256) void k_transform_kernel(float* __restrict__ Kp) {
  int wid  = blockIdx.x * 4 + (threadIdx.x >> 6);
  int lane = threadIdx.x & 63;
  int hs = wid & 15;
  int bt = wid >> 4;
  int t  = bt & (T_SEQ - 1);
  float* row = Kp + (size_t)bt * 1024 + hs * 64;
  float x = row[lane];
  int p = lane & 31;
  float x1 = __shfl(x, 2 * p, 64);
  float x2 = __shfl(x, 2 * p + 1, 64);
  float invf = exp2f(-LOG2_10000 * (float)(2 * p) * (1.0f / 64.0f));
  float ang = (float)t * invf;
  float sn, cs;
  sincosf(ang, &sn, &cs);
  float xr = (lane < 32) ? (x1 * cs - x2 * sn) : (x1 * sn + x2 * cs);
  float ss = wave_sum64(xr * xr);
  row[lane] = xr * rsqrtf(ss);
}

// Vsum[b][h][d] = sum_t Vp[(b*T+t)*4096 + h*64 + d]
__global__ void vsum_kernel(const float* __restrict__ Vp, float* __restrict__ Vsum) {
  int bh = blockIdx.x;
  int d  = threadIdx.x;
  int b = bh >> 6, h = bh & 63;
  float s = 0.f;
  for (int tt = 0; tt < T_SEQ; ++tt)
    s += Vp[(size_t)(b * T_SEQ + tt) * 4096 + h * 64 + d];
  Vsum[bh * 64 + d] = s;
}

// ------------------------------------------------------------------
// Banded attention; logit-0 masking handled algebraically:
//   num_d = S_all[d] + sum_band (e^w - 1) v_d + es * vnull_d
//   Z     = T + sum_band (e^w - 1) + es,   es = exp(tanh(sink))
// ------------------------------------------------------------------
__global__ __launch_bounds__(256) void attn_kernel(
    const float* __restrict__ Qp, const float* __restrict__ Khat,
    const float* __restrict__ Vp, const float* __restrict__ Vsum,
    const float* __restrict__ sink, const float* __restrict__ vnull,
    float* __restrict__ mctx)
{
  __shared__ __align__(16) float qs[32][68];
  __shared__ __align__(16) float ks[64][68];
  __shared__ __align__(16) float vs[64][68];
  __shared__ __align__(16) float pe[32][64];

  const int tid = threadIdx.x;
  const int blk = blockIdx.x;
  const int qt  = blk & 31;
  const int hs  = (blk >> 5) & 15;
  const int b   = blk >> 9;
  const int qt0 = qt * 32;
  const int qi  = tid >> 3;
  const int u   = tid & 7;
  const int t   = qt0 + qi;

  const int HCFG[4] = {16, 128, 128, 512};
  const int GCFG[4] = {0, 16, 0, 144};

  float macc[8];
#pragma unroll
  for (int i = 0; i < 8; ++i) macc[i] = 0.f;

  for (int br = 0; br < 4; ++br) {
    const int h = br * 16 + hs;
    const int hmax = HCFG[br], g = GCFG[br];

    __syncthreads();
#pragma unroll
    for (int q4 = 0; q4 < 2; ++q4) {
      int f = tid + 256 * q4;
      int r = f >> 4, c4 = f & 15;
      *reinterpret_cast<float4*>(&qs[r][c4 * 4]) =
          *reinterpret_cast<const float4*>(
              &Qp[(size_t)(b * T_SEQ + qt0 + r) * 4096 + h * 64 + c4 * 4]);
    }
    float outv[8];
#pragma unroll
    for (int i = 0; i < 8; ++i) outv[i] = 0.f;
    float zpart = 0.f;
    __syncthreads();

    int klo = qt0 - (hmax - 1); if (klo < 0) klo = 0;
    int khi = qt0 + 31 - g;     if (khi > T_SEQ - 1) khi = T_SEQ - 1;

    for (int j0 = klo; j0 <= khi; j0 += 64) {
      __syncthreads();
#pragma unroll
      for (int q4 = 0; q4 < 4; ++q4) {
        int f = tid + 256 * q4;
        int r = f >> 4, c4 = f & 15;
        int j = j0 + r;
        float4 kv = make_float4(0.f, 0.f, 0.f, 0.f);
        float4 vv = make_float4(0.f, 0.f, 0.f, 0.f);
        if (j < T_SEQ) {
          kv = *reinterpret_cast<const float4*>(
              &Khat[(size_t)(b * T_SEQ + j) * 1024 + hs * 64 + c4 * 4]);
          vv = *reinterpret_cast<const float4*>(
              &Vp[(size_t)(b * T_SEQ + j) * 4096 + h * 64 + c4 * 4]);
        }
        *reinterpret_cast<float4*>(&ks[r][c4 * 4]) = kv;
        *reinterpret_cast<float4*>(&vs[r][c4 * 4]) = vv;
      }
      __syncthreads();

      float s[8];
#pragma unroll
      for (int w = 0; w < 8; ++w) s[w] = 0.f;
#pragma unroll
      for (int d4 = 0; d4 < 16; ++d4) {
        float4 qv = *reinterpret_cast<const float4*>(&qs[qi][d4 * 4]);
#pragma unroll
        for (int w = 0; w < 8; ++w) {
          float4 kv = *reinterpret_cast<const float4*>(&ks[u + 8 * w][d4 * 4]);
          s[w] += qv.x * kv.x + qv.y * kv.y + qv.z * kv.z + qv.w * kv.w;
        }
      }
#pragma unroll
      for (int w = 0; w < 8; ++w) {
        int jj = u + 8 * w;
        int j = j0 + jj;
        int dist = t - j;
        bool inband = (dist >= g) && (dist < hmax) && (j < T_SEQ);
        float val = inband ? (expf(s[w]) - 1.0f) : 0.f;
        pe[qi][jj] = val;
        zpart += val;
      }
      __syncthreads();

#pragma unroll 4
      for (int jj4 = 0; jj4 < 16; ++jj4) {
        float4 pw = *reinterpret_cast<const float4*>(&pe[qi][jj4 * 4]);
        if (pw.x == 0.f && pw.y == 0.f && pw.z == 0.f && pw.w == 0.f) continue;
        float pwa[4] = {pw.x, pw.y, pw.z, pw.w};
#pragma unroll
        for (int e = 0; e < 4; ++e) {
          int jj = jj4 * 4 + e;
          float4 v0 = *reinterpret_cast<const float4*>(&vs[jj][u * 8]);
          float4 v1 = *reinterpret_cast<const float4*>(&vs[jj][u * 8 + 4]);
          float wv = pwa[e];
          outv[0] = fmaf(wv, v0.x, outv[0]);
          outv[1] = fmaf(wv, v0.y, outv[1]);
          outv[2] = fmaf(wv, v0.z, outv[2]);
          outv[3] = fmaf(wv, v0.w, outv[3]);
          outv[4] = fmaf(wv, v1.x, outv[4]);
          outv[5] = fmaf(wv, v1.y, outv[5]);
          outv[6] = fmaf(wv, v1.z, outv[6]);
          outv[7] = fmaf(wv, v1.w, outv[7]);
        }
      }
    }

    float z = zpart;
    z += __shfl_xor(z, 1, 64);
    z += __shfl_xor(z, 2, 64);
    z += __shfl_xor(z, 4, 64);
    float es = expf(tanhf(sink[h]));
    float invZ = 1.0f / ((float)T_SEQ + z + es);
#pragma unroll
    for (int i = 0; i < 8; ++i) {
      int d = u * 8 + i;
      float num = outv[i] + Vsum[(b * 64 + h) * 64 + d] + es * vnull[h * 64 + d];
      macc[i] += num * invZ;
    }
  }

#pragma unroll
  for (int i = 0; i < 8; ++i) {
    int d = u * 8 + i;
    mctx[(size_t)(b * T_SEQ + t) * 1024 + hs * 64 + d] = 0.25f * macc[i];
  }
}

extern "C" void kernel_launch(void* const* d_in, const int* in_sizes, int n_in,
                              void* d_out, int out_size, void* d_ws, size_t ws_size,
                              hipStream_t stream) {
  (void)in_sizes; (void)n_in; (void)out_size; (void)ws_size;
  const float* X    = (const float*)d_in[0];
  const float* WQ   = (const float*)d_in[1];
  const float* bQ   = (const float*)d_in[2];
  const float* WK   = (const float*)d_in[3];
  const float* bK   = (const float*)d_in[4];
  const float* WV   = (const float*)d_in[5];
  const float* bV   = (const float*)d_in[6];
  const float* WO   = (const float*)d_in[7];
  const float* bO   = (const float*)d_in[8];
  const float* sink = (const float*)d_in[9];
  const float* vnul = (const float*)d_in[10];
  float* Y = (float*)d_out;

  char* p = (char*)d_ws;
  float* Qp    = (float*)p; p += (size_t)2048 * 4096 * 4;   // 32 MB
  float* Vp    = (float*)p; p += (size_t)2048 * 4096 * 4;   // 32 MB
  float* Kp    = (float*)p; p += (size_t)2048 * 1024 * 4;   //  8 MB
  float* mctx  = (float*)p; p += (size_t)2048 * 1024 * 4;   //  8 MB
  float* Vsum  = (float*)p; p += (size_t)128 * 64 * 4;
  u16*   Xb    = (u16*)p;   p += (size_t)2048 * 1024 * 2;   //  4 MB
  u16*   WQt   = (u16*)p;   p += (size_t)4096 * 1024 * 2;   //  8 MB
  u16*   WKt   = (u16*)p;   p += (size_t)1024 * 1024 * 2;   //  2 MB
  u16*   WVt   = (u16*)p;   p += (size_t)4096 * 1024 * 2;   //  8 MB
  u16*   WOt   = (u16*)p;   p += (size_t)1024 * 1024 * 2;   //  2 MB
  u16*   mctxb = (u16*)p;   p += (size_t)2048 * 1024 * 2;   //  4 MB

  dim3 blk(256);
  cvt_bf16_kernel<<<1024, blk, 0, stream>>>(X, Xb, 262144);
  transpose_cvt_kernel<<<dim3(128, 32), blk, 0, stream>>>(WQ, WQt, 4096, 1024);
  transpose_cvt_kernel<<<dim3(32, 32),  blk, 0, stream>>>(WK, WKt, 1024, 1024);
  transpose_cvt_kernel<<<dim3(128, 32), blk, 0, stream>>>(WV, WVt, 4096, 1024);
  transpose_cvt_kernel<<<dim3(32, 32),  blk, 0, stream>>>(WO, WOt, 1024, 1024);

  gemm_bf16_kernel<<<dim3(32, 16), blk, 0, stream>>>(Xb, WQt, bQ, Qp, 2048, 4096, 1024);
  gemm_bf16_kernel<<<dim3(8, 16),  blk, 0, stream>>>(Xb, WKt, bK, Kp, 2048, 1024, 1024);
  gemm_bf16_kernel<<<dim3(32, 16), blk, 0, stream>>>(Xb, WVt, bV, Vp, 2048, 4096, 1024);

  q_transform_kernel<<<(2048 * 64) / 4, blk, 0, stream>>>(Qp);
  k_transform_kernel<<<(2048 * 16) / 4, blk, 0, stream>>>(Kp);
  vsum_kernel<<<128, 64, 0, stream>>>(Vp, Vsum);
  attn_kernel<<<2 * 16 * 32, blk, 0, stream>>>(Qp, Kp, Vp, Vsum, sink, vnul, mctx);

  cvt_bf16_kernel<<<1024, blk, 0, stream>>>(mctx, mctxb, 262144);
  gemm_bf16_kernel<<<dim3(8, 16), blk, 0, stream>>>(mctxb, WOt, bO, Y, 2048, 1024, 1024);
}

// Round 3
// 282.099 us; speedup vs baseline: 3.5088x; 1.4555x over previous
//
#include <hip/hip_runtime.h>
#include <hip/hip_bf16.h>
#include <math.h>

#define T_SEQ 1024
#define LOG2_10000 13.287712379549449f

typedef unsigned short u16;
typedef unsigned int u32;
typedef __attribute__((ext_vector_type(8))) short bf16x8;
typedef __attribute__((ext_vector_type(4))) float f32x4;

__device__ __forceinline__ void gload16(const u16* g, const u16* s) {
  __builtin_amdgcn_global_load_lds(
      (const __attribute__((address_space(1))) void*)g,
      (__attribute__((address_space(3))) void*)s, 16, 0, 0);
}

__device__ __forceinline__ u16 f2bf(float x) {
  __hip_bfloat16 h = __float2bfloat16(x);
  return *reinterpret_cast<u16*>(&h);
}
__device__ __forceinline__ float bf2f(u16 x) {
  __hip_bfloat16 h = *reinterpret_cast<__hip_bfloat16*>(&x);
  return __bfloat162float(h);
}

// ------------------------------------------------------------------
// fp32 -> bf16 elementwise (8 elems / thread)
// ------------------------------------------------------------------
__global__ __launch_bounds__(256) void cvt_bf16_kernel(
    const float* __restrict__ in, u16* __restrict__ out, int n8) {
  int i = blockIdx.x * 256 + threadIdx.x;
  if (i >= n8) return;
  float4 a = reinterpret_cast<const float4*>(in)[2 * i];
  float4 b = reinterpret_cast<const float4*>(in)[2 * i + 1];
  u16 o[8] = {f2bf(a.x), f2bf(a.y), f2bf(a.z), f2bf(a.w),
              f2bf(b.x), f2bf(b.y), f2bf(b.z), f2bf(b.w)};
  reinterpret_cast<uint4*>(out)[i] = *reinterpret_cast<const uint4*>(o);
}

// ------------------------------------------------------------------
// W[K][N] fp32 -> Wt[N][K] bf16 (32x32 LDS tile transpose)
// ------------------------------------------------------------------
__global__ __launch_bounds__(256) void transpose_cvt_kernel(
    const float* __restrict__ W, u16* __restrict__ Wt, int N, int K) {
  __shared__ float tile[32][33];
  int n0 = blockIdx.x * 32, k0 = blockIdx.y * 32;
  int t = threadIdx.x;
  int r = t >> 3, c4 = (t & 7) * 4;
  float4 v = *reinterpret_cast<const float4*>(&W[(size_t)(k0 + r) * N + n0 + c4]);
  tile[r][c4 + 0] = v.x;
  tile[r][c4 + 1] = v.y;
  tile[r][c4 + 2] = v.z;
  tile[r][c4 + 3] = v.w;
  __syncthreads();
  u16 o[4];
#pragma unroll
  for (int i = 0; i < 4; ++i) o[i] = f2bf(tile[c4 + i][r]);
  *reinterpret_cast<uint2*>(&Wt[(size_t)(n0 + r) * K + k0 + c4]) =
      *reinterpret_cast<const uint2*>(o);
}

// ------------------------------------------------------------------
// bf16 MFMA GEMM: C[MxN] = A[MxK] @ Bt[NxK]^T + bias
// 128x128 tile, BK=32, 256 threads = 4 waves, 4x4 frags/wave.
// BF16OUT: write bf16 (u16) instead of fp32.
// ------------------------------------------------------------------
template <bool BF16OUT>
__global__ __launch_bounds__(256) void gemm_bf16_kernel(
    const u16* __restrict__ Ab, const u16* __restrict__ Bt,
    const float* __restrict__ bias, void* __restrict__ Cv,
    int M, int N, int K)
{
  __shared__ __align__(16) u16 sA[128 * 32];
  __shared__ __align__(16) u16 sB[128 * 32];
  const int tid = threadIdx.x;
  const int lane = tid & 63;
  const int wv = tid >> 6;
  const int wm = wv >> 1, wn = wv & 1;
  const int m0 = blockIdx.y * 128, n0 = blockIdx.x * 128;

  f32x4 acc[4][4];
#pragma unroll
  for (int i = 0; i < 4; ++i)
#pragma unroll
    for (int j = 0; j < 4; ++j) acc[i][j] = (f32x4){0.f, 0.f, 0.f, 0.f};

  const int r0 = tid >> 2, kc = tid & 3;
  const u16* a_src0 = Ab + (size_t)(m0 + r0) * K + kc * 8;
  const u16* a_src1 = Ab + (size_t)(m0 + 64 + r0) * K + kc * 8;
  const u16* b_src0 = Bt + (size_t)(n0 + r0) * K + kc * 8;
  const u16* b_src1 = Bt + (size_t)(n0 + 64 + r0) * K + kc * 8;
  u16* sA0 = sA + (size_t)(wv * 64) * 8;
  u16* sA1 = sA + (size_t)(256 + wv * 64) * 8;
  u16* sB0 = sB + (size_t)(wv * 64) * 8;
  u16* sB1 = sB + (size_t)(256 + wv * 64) * 8;

  const int arow = wm * 64 + (lane & 15);
  const int brow = wn * 64 + (lane & 15);
  const int kcol = (lane >> 4) * 8;

  for (int k0 = 0; k0 < K; k0 += 32) {
    __syncthreads();
    gload16(a_src0 + k0, sA0);
    gload16(a_src1 + k0, sA1);
    gload16(b_src0 + k0, sB0);
    gload16(b_src1 + k0, sB1);
    __syncthreads();
    bf16x8 af[4], bfv[4];
#pragma unroll
    for (int mi = 0; mi < 4; ++mi)
      af[mi] = *reinterpret_cast<const bf16x8*>(&sA[(arow + mi * 16) * 32 + kcol]);
#pragma unroll
    for (int ni = 0; ni < 4; ++ni)
      bfv[ni] = *reinterpret_cast<const bf16x8*>(&sB[(brow + ni * 16) * 32 + kcol]);
#pragma unroll
    for (int mi = 0; mi < 4; ++mi)
#pragma unroll
      for (int ni = 0; ni < 4; ++ni)
        acc[mi][ni] = __builtin_amdgcn_mfma_f32_16x16x32_bf16(
            af[mi], bfv[ni], acc[mi][ni], 0, 0, 0);
  }

  const int crow = m0 + wm * 64 + (lane >> 4) * 4;
  const int ccol = n0 + wn * 64 + (lane & 15);
#pragma unroll
  for (int mi = 0; mi < 4; ++mi)
#pragma unroll
    for (int ni = 0; ni < 4; ++ni) {
      int col = ccol + ni * 16;
      float bv = bias[col];
#pragma unroll
      for (int r = 0; r < 4; ++r) {
        float val = acc[mi][ni][r] + bv;
        size_t idx = (size_t)(crow + mi * 16 + r) * N + col;
        if (BF16OUT) ((u16*)Cv)[idx] = f2bf(val);
        else ((float*)Cv)[idx] = val;
      }
    }
}

__device__ __forceinline__ float wave_sum64(float v) {
  v += __shfl_xor(v, 1, 64);
  v += __shfl_xor(v, 2, 64);
  v += __shfl_xor(v, 4, 64);
  v += __shfl_xor(v, 8, 64);
  v += __shfl_xor(v, 16, 64);
  v += __shfl_xor(v, 32, 64);
  return v;
}

// rms_norm + rope, in place on bf16 Qb[(b*T+t)*4096 + h*64 + d]
__global__ __launch_bounds__(256) void q_transform_kernel(u16* __restrict__ Qb) {
  int wid  = blockIdx.x * 4 + (threadIdx.x >> 6);
  int lane = threadIdx.x & 63;
  int h  = wid & 63;
  int bt = wid >> 6;
  int t  = bt & (T_SEQ - 1);
  u16* row = Qb + (size_t)bt * 4096 + h * 64;
  float x  = bf2f(row[lane]);
  float ss = wave_sum64(x * x);
  float xn = x * rsqrtf(ss * (1.0f / 64.0f) + 1.1920929e-7f);
  int p = lane & 31;
  float x1 = __shfl(xn, 2 * p, 64);
  float x2 = __shfl(xn, 2 * p + 1, 64);
  float invf = exp2f(-LOG2_10000 * (float)(2 * p) * (1.0f / 64.0f));
  float ang = (float)t * invf;
  float sn, cs;
  sincosf(ang, &sn, &cs);
  row[lane] = f2bf((lane < 32) ? (x1 * cs - x2 * sn) : (x1 * sn + x2 * cs));
}

// rope + unit-normalize, in place on bf16 Kb
__global__ __launch_bounds__(256) void k_transform_kernel(u16* __restrict__ Kb) {
  int wid  = blockIdx.x * 4 + (threadIdx.x >> 6);
  int lane = threadIdx.x & 63;
  int hs = wid & 15;
  int bt = wid >> 4;
  int t  = bt & (T_SEQ - 1);
  u16* row = Kb + (size_t)bt * 1024 + hs * 64;
  float x = bf2f(row[lane]);
  int p = lane & 31;
  float x1 = __shfl(x, 2 * p, 64);
  float x2 = __shfl(x, 2 * p + 1, 64);
  float invf = exp2f(-LOG2_10000 * (float)(2 * p) * (1.0f / 64.0f));
  float ang = (float)t * invf;
  float sn, cs;
  sincosf(ang, &sn, &cs);
  float xr = (lane < 32) ? (x1 * cs - x2 * sn) : (x1 * sn + x2 * cs);
  float ss = wave_sum64(xr * xr);
  row[lane] = f2bf(xr * rsqrtf(ss));
}

// Vsum[b][h][d] = sum_t V, bf16 in, fp32 out
__global__ __launch_bounds__(256) void vsum_kernel(const u16* __restrict__ Vb,
                                                   float* __restrict__ Vsum) {
  __shared__ float red[256];
  int bh = blockIdx.x;
  int t  = threadIdx.x;
  int d = t & 63, tq = t >> 6;
  int b = bh >> 6, h = bh & 63;
  float s = 0.f;
  for (int tt = tq; tt < T_SEQ; tt += 4)
    s += bf2f(Vb[(size_t)(b * T_SEQ + tt) * 4096 + h * 64 + d]);
  red[t] = s;
  __syncthreads();
  if (t < 64)
    Vsum[bh * 64 + t] = red[t] + red[t + 64] + red[t + 128] + red[t + 192];
}

// ------------------------------------------------------------------
// MFMA banded attention. Per block: (b, hs, 32-query tile), 4 waves.
// Logit-0 masking algebraic: num = Vsum + sum_band (e^s - 1) v + es*vnull
//                            Z   = T + sum_band (e^s - 1) + es
// LDS tiles pitch 64 u16 (128B), XOR swizzle byte ^= ((row&7)<<4).
// Q,K staged via global_load_lds with pre-swizzled global source;
// Vt reg-transposed with swizzled pair-packed b32 writes.
// ------------------------------------------------------------------
__global__ __launch_bounds__(256) void attn_mfma_kernel(
    const u16* __restrict__ Qb, const u16* __restrict__ Kb,
    const u16* __restrict__ Vb, const float* __restrict__ Vsum,
    const float* __restrict__ sink, const float* __restrict__ vnull,
    float* __restrict__ mctx)
{
  __shared__ __align__(16) u16 sQ[32 * 64];
  __shared__ __align__(16) u16 sK[64 * 64];
  __shared__ __align__(16) u16 sVt[64 * 64];
  __shared__ __align__(16) u16 sP[32 * 64];
  __shared__ float z_lds[2][32];

  int blk = blockIdx.x;
  blk = (blk & 7) * 128 + (blk >> 3);   // XCD-chunked remap (bijective, 1024%8==0)
  const int qt  = blk & 31;
  const int hs  = (blk >> 5) & 15;
  const int b   = blk >> 9;
  const int qt0 = qt * 32;

  const int tid  = threadIdx.x;
  const int lane = tid & 63;
  const int wv   = tid >> 6;
  const int l15  = lane & 15;
  const int l4   = lane >> 4;
  const int hq   = wv & 1;    // q-half for QK and PV
  const int jp   = wv >> 1;   // j-tile-pair for QK; d-tile-pair for PV
  const int dp   = wv >> 1;

  constexpr int HCFG[4] = {16, 128, 128, 512};
  constexpr int GCFG[4] = {0, 16, 0, 144};

  f32x4 macc[2];
  macc[0] = (f32x4){0.f, 0.f, 0.f, 0.f};
  macc[1] = (f32x4){0.f, 0.f, 0.f, 0.f};

#pragma unroll
  for (int br = 0; br < 4; ++br) {
    const int h = br * 16 + hs;
    const int hmax = HCFG[br], g = GCFG[br];

    // ---- stage Q (32x64 bf16), swizzled source, linear LDS dest ----
    {
      int c = tid;                     // 256 chunks of 16B
      int qrow = c >> 3, i = c & 7;
      gload16(Qb + (size_t)(b * T_SEQ + qt0 + qrow) * 4096 + h * 64 +
                  8 * (i ^ (qrow & 7)),
              sQ + wv * 512);
    }
    __syncthreads();

    // A-fragments for Q (hoisted per branch): row = hq*16+l15
    bf16x8 afQ[2];
    {
      int qrow = hq * 16 + l15;
#pragma unroll
      for (int kh = 0; kh < 2; ++kh) {
        int cs = (4 * kh + l4) ^ (qrow & 7);
        afQ[kh] = *reinterpret_cast<const bf16x8*>(&sQ[qrow * 64 + cs * 8]);
      }
    }

    f32x4 outv[2];
    outv[0] = (f32x4){0.f, 0.f, 0.f, 0.f};
    outv[1] = (f32x4){0.f, 0.f, 0.f, 0.f};
    float zacc[4] = {0.f, 0.f, 0.f, 0.f};

    int klo = qt0 - (hmax - 1); if (klo < 0) klo = 0;
    int khi = qt0 + 31 - g;     if (khi > T_SEQ - 1) khi = T_SEQ - 1;

    for (int j0 = klo; j0 <= khi; j0 += 64) {
      __syncthreads();  // staging vs previous chunk's readers
      // ---- stage K (64x64), 2 gloads/thread, swizzled source ----
      {
        int c = tid;
        int jr = c >> 3, i = c & 7;
        int jc = j0 + jr; if (jc > T_SEQ - 1) jc = T_SEQ - 1;
        gload16(Kb + (size_t)(b * T_SEQ + jc) * 1024 + hs * 64 +
                    8 * (i ^ (jr & 7)),
                sK + wv * 512);
        c = tid + 256;
        jr = c >> 3; i = c & 7;
        jc = j0 + jr; if (jc > T_SEQ - 1) jc = T_SEQ - 1;
        gload16(Kb + (size_t)(b * T_SEQ + jc) * 1024 + hs * 64 +
                    8 * (i ^ (jr & 7)),
                sK + 2048 + wv * 512);
      }
      // ---- stage V^T (reg transpose, pair-packed b32 swizzled writes) ----
      {
        int jp2 = tid & 31, dg = tid >> 5;
        int ja = j0 + 2 * jp2, jb = ja + 1;
        if (ja > T_SEQ - 1) ja = T_SEQ - 1;
        if (jb > T_SEQ - 1) jb = T_SEQ - 1;
        bf16x8 va = *reinterpret_cast<const bf16x8*>(
            &Vb[(size_t)(b * T_SEQ + ja) * 4096 + h * 64 + dg * 8]);
        bf16x8 vb = *reinterpret_cast<const bf16x8*>(
            &Vb[(size_t)(b * T_SEQ + jb) * 4096 + h * 64 + dg * 8]);
#pragma unroll
        for (int e = 0; e < 8; ++e) {
          int d = dg * 8 + e;
          u32 pack = (u32)(u16)va[e] | ((u32)(u16)vb[e] << 16);
          *reinterpret_cast<u32*>(
              (char*)sVt + d * 128 + ((4 * jp2) ^ ((d & 7) << 4))) = pack;
        }
      }
      __syncthreads();

      // ---- QK^T: wave computes S[hq*16..+15][jp*32..+31] ----
      f32x4 sfr[2];
#pragma unroll
      for (int n = 0; n < 2; ++n) {
        int jt = jp * 2 + n;
        f32x4 acc = (f32x4){0.f, 0.f, 0.f, 0.f};
        int krow = jt * 16 + l15;
#pragma unroll
        for (int kh = 0; kh < 2; ++kh) {
          int cs = (4 * kh + l4) ^ (krow & 7);
          bf16x8 bk = *reinterpret_cast<const bf16x8*>(&sK[krow * 64 + cs * 8]);
          acc = __builtin_amdgcn_mfma_f32_16x16x32_bf16(afQ[kh], bk, acc, 0, 0, 0);
        }
        sfr[n] = acc;
      }
      // ---- P = inband ? e^s - 1 : 0 ; z accumulate ; bf16 -> sP ----
#pragma unroll
      for (int n = 0; n < 2; ++n) {
        int jloc = (jp * 2 + n) * 16 + l15;
        int jabs = j0 + jloc;
#pragma unroll
        for (int r = 0; r < 4; ++r) {
          int q_r = hq * 16 + l4 * 4 + r;
          int dist = (qt0 + q_r) - jabs;
          bool inband = (dist >= g) & (dist < hmax) & (jabs < T_SEQ);
          float pv = inband ? (__expf(sfr[n][r]) - 1.0f) : 0.0f;
          zacc[r] += pv;
          *reinterpret_cast<u16*>(
              (char*)sP + q_r * 128 + ((2 * jloc) ^ ((q_r & 7) << 4))) = f2bf(pv);
        }
      }
      __syncthreads();

      // ---- PV: out[hq*16..+15][dp*32..+31] += P @ V^T ----
      bf16x8 afP[2];
      {
        int prow = hq * 16 + l15;
#pragma unroll
        for (int kh = 0; kh < 2; ++kh) {
          int cs = (4 * kh + l4) ^ (prow & 7);
          afP[kh] = *reinterpret_cast<const bf16x8*>(&sP[prow * 64 + cs * 8]);
        }
      }
#pragma unroll
      for (int n = 0; n < 2; ++n) {
        int drow = (dp * 2 + n) * 16 + l15;
#pragma unroll
        for (int kh = 0; kh < 2; ++kh) {
          int cs = (4 * kh + l4) ^ (drow & 7);
          bf16x8 bv = *reinterpret_cast<const bf16x8*>(&sVt[drow * 64 + cs * 8]);
          outv[n] = __builtin_amdgcn_mfma_f32_16x16x32_bf16(afP[kh], bv, outv[n], 0, 0, 0);
        }
      }
    }

    // ---- branch epilogue: z reduce, normalize, accumulate macc ----
    __syncthreads();
#pragma unroll
    for (int r = 0; r < 4; ++r) {
      zacc[r] += __shfl_xor(zacc[r], 1, 64);
      zacc[r] += __shfl_xor(zacc[r], 2, 64);
      zacc[r] += __shfl_xor(zacc[r], 4, 64);
      zacc[r] += __shfl_xor(zacc[r], 8, 64);
    }
    if (l15 == 0) {
#pragma unroll
      for (int r = 0; r < 4; ++r)
        z_lds[jp][hq * 16 + l4 * 4 + r] = zacc[r];
    }
    __syncthreads();

    float es = __expf(tanhf(sink[h]));
#pragma unroll
    for (int n = 0; n < 2; ++n) {
      int d = (dp * 2 + n) * 16 + l15;
      float vs = Vsum[(b * 64 + h) * 64 + d];
      float vn = vnull[h * 64 + d];
#pragma unroll
      for (int r = 0; r < 4; ++r) {
        int q_r = hq * 16 + l4 * 4 + r;
        float z = z_lds[0][q_r] + z_lds[1][q_r];
        float invZ = 1.0f / (1024.0f + z + es);
        macc[n][r] += (outv[n][r] + vs + es * vn) * invZ;
      }
    }
  }

#pragma unroll
  for (int n = 0; n < 2; ++n) {
    int d = (dp * 2 + n) * 16 + l15;
#pragma unroll
    for (int r = 0; r < 4; ++r) {
      int q_r = hq * 16 + l4 * 4 + r;
      mctx[(size_t)(b * T_SEQ + qt0 + q_r) * 1024 + hs * 64 + d] =
          0.25f * macc[n][r];
    }
  }
}

extern "C" void kernel_launch(void* const* d_in, const int* in_sizes, int n_in,
                              void* d_out, int out_size, void* d_ws, size_t ws_size,
                              hipStream_t stream) {
  (void)in_sizes; (void)n_in; (void)out_size; (void)ws_size;
  const float* X    = (const float*)d_in[0];
  const float* WQ   = (const float*)d_in[1];
  const float* bQ   = (const float*)d_in[2];
  const float* WK   = (const float*)d_in[3];
  const float* bK   = (const float*)d_in[4];
  const float* WV   = (const float*)d_in[5];
  const float* bV   = (const float*)d_in[6];
  const float* WO   = (const float*)d_in[7];
  const float* bO   = (const float*)d_in[8];
  const float* sink = (const float*)d_in[9];
  const float* vnul = (const float*)d_in[10];
  float* Y = (float*)d_out;

  char* p = (char*)d_ws;
  u16*   Xb    = (u16*)p;   p += (size_t)2048 * 1024 * 2;   //  4 MB
  u16*   WQt   = (u16*)p;   p += (size_t)4096 * 1024 * 2;   //  8 MB
  u16*   WKt   = (u16*)p;   p += (size_t)1024 * 1024 * 2;   //  2 MB
  u16*   WVt   = (u16*)p;   p += (size_t)4096 * 1024 * 2;   //  8 MB
  u16*   WOt   = (u16*)p;   p += (size_t)1024 * 1024 * 2;   //  2 MB
  u16*   Qbf   = (u16*)p;   p += (size_t)2048 * 4096 * 2;   // 16 MB
  u16*   Kbf   = (u16*)p;   p += (size_t)2048 * 1024 * 2;   //  4 MB
  u16*   Vbf   = (u16*)p;   p += (size_t)2048 * 4096 * 2;   // 16 MB
  float* Vsum  = (float*)p; p += (size_t)128 * 64 * 4;
  float* mctx  = (float*)p; p += (size_t)2048 * 1024 * 4;   //  8 MB
  u16*   mctxb = (u16*)p;   p += (size_t)2048 * 1024 * 2;   //  4 MB

  dim3 blk(256);
  cvt_bf16_kernel<<<1024, blk, 0, stream>>>(X, Xb, 262144);
  transpose_cvt_kernel<<<dim3(128, 32), blk, 0, stream>>>(WQ, WQt, 4096, 1024);
  transpose_cvt_kernel<<<dim3(32, 32),  blk, 0, stream>>>(WK, WKt, 1024, 1024);
  transpose_cvt_kernel<<<dim3(128, 32), blk, 0, stream>>>(WV, WVt, 4096, 1024);
  transpose_cvt_kernel<<<dim3(32, 32),  blk, 0, stream>>>(WO, WOt, 1024, 1024);

  gemm_bf16_kernel<true><<<dim3(32, 16), blk, 0, stream>>>(Xb, WQt, bQ, Qbf, 2048, 4096, 1024);
  gemm_bf16_kernel<true><<<dim3(8, 16),  blk, 0, stream>>>(Xb, WKt, bK, Kbf, 2048, 1024, 1024);
  gemm_bf16_kernel<true><<<dim3(32, 16), blk, 0, stream>>>(Xb, WVt, bV, Vbf, 2048, 4096, 1024);

  q_transform_kernel<<<(2048 * 64) / 4, blk, 0, stream>>>(Qbf);
  k_transform_kernel<<<(2048 * 16) / 4, blk, 0, stream>>>(Kbf);
  vsum_kernel<<<128, blk, 0, stream>>>(Vbf, Vsum);

  attn_mfma_kernel<<<1024, blk, 0, stream>>>(Qbf, Kbf, Vbf, Vsum, sink, vnul, mctx);

  cvt_bf16_kernel<<<1024, blk, 0, stream>>>(mctx, mctxb, 262144);
  gemm_bf16_kernel<false><<<dim3(8, 16), blk, 0, stream>>>(mctxb, WOt, bO, Y, 2048, 1024, 1024);
}

// Round 4
// 240.845 us; speedup vs baseline: 4.1099x; 1.1713x over previous
//
#include <hip/hip_runtime.h>
#include <hip/hip_bf16.h>
#include <math.h>

#define T_SEQ 1024
#define LOG2_10000 13.287712379549449f

typedef unsigned short u16;
typedef unsigned int u32;
typedef __attribute__((ext_vector_type(8))) short bf16x8;
typedef __attribute__((ext_vector_type(4))) float f32x4;

__device__ __forceinline__ void gload16(const u16* g, const u16* s) {
  __builtin_amdgcn_global_load_lds(
      (const __attribute__((address_space(1))) void*)g,
      (__attribute__((address_space(3))) void*)s, 16, 0, 0);
}

__device__ __forceinline__ u16 f2bf(float x) {
  __hip_bfloat16 h = __float2bfloat16(x);
  return *reinterpret_cast<u16*>(&h);
}
__device__ __forceinline__ float bf2f(u16 x) {
  __hip_bfloat16 h = *reinterpret_cast<__hip_bfloat16*>(&x);
  return __bfloat162float(h);
}

// ------------------------------------------------------------------
// fp32 -> bf16 elementwise (8 elems / thread)
// ------------------------------------------------------------------
__global__ __launch_bounds__(256) void cvt_bf16_kernel(
    const float* __restrict__ in, u16* __restrict__ out, int n8) {
  int i = blockIdx.x * 256 + threadIdx.x;
  if (i >= n8) return;
  float4 a = reinterpret_cast<const float4*>(in)[2 * i];
  float4 b = reinterpret_cast<const float4*>(in)[2 * i + 1];
  u16 o[8] = {f2bf(a.x), f2bf(a.y), f2bf(a.z), f2bf(a.w),
              f2bf(b.x), f2bf(b.y), f2bf(b.z), f2bf(b.w)};
  reinterpret_cast<uint4*>(out)[i] = *reinterpret_cast<const uint4*>(o);
}

// ------------------------------------------------------------------
// W[K][N] fp32 -> Wt[N][K] bf16 (32x32 LDS tile transpose)
// ------------------------------------------------------------------
__global__ __launch_bounds__(256) void transpose_cvt_kernel(
    const float* __restrict__ W, u16* __restrict__ Wt, int N, int K) {
  __shared__ float tile[32][33];
  int n0 = blockIdx.x * 32, k0 = blockIdx.y * 32;
  int t = threadIdx.x;
  int r = t >> 3, c4 = (t & 7) * 4;
  float4 v = *reinterpret_cast<const float4*>(&W[(size_t)(k0 + r) * N + n0 + c4]);
  tile[r][c4 + 0] = v.x;
  tile[r][c4 + 1] = v.y;
  tile[r][c4 + 2] = v.z;
  tile[r][c4 + 3] = v.w;
  __syncthreads();
  u16 o[4];
#pragma unroll
  for (int i = 0; i < 4; ++i) o[i] = f2bf(tile[c4 + i][r]);
  *reinterpret_cast<uint2*>(&Wt[(size_t)(n0 + r) * K + k0 + c4]) =
      *reinterpret_cast<const uint2*>(o);
}

// ------------------------------------------------------------------
// rope tables: ctab/stab[t*32+p] = cos/sin(t * 10000^(-2p/64))
// ------------------------------------------------------------------
__global__ __launch_bounds__(256) void rope_table_kernel(
    float* __restrict__ ctab, float* __restrict__ stab) {
  int id = blockIdx.x * 256 + threadIdx.x;  // 32768
  int t = id >> 5, p = id & 31;
  float invf = exp2f(-LOG2_10000 * (float)(2 * p) * (1.0f / 64.0f));
  float ang = (float)t * invf;
  float sn, cs;
  sincosf(ang, &sn, &cs);
  ctab[id] = cs;
  stab[id] = sn;
}

// ------------------------------------------------------------------
// Xsum chain: Vsum[b][n] = (sum_t X[b,t,:]) @ WV[:,n] + T*bV[n]
// ------------------------------------------------------------------
__global__ __launch_bounds__(256) void xsum_part_kernel(
    const float* __restrict__ X, float* __restrict__ part) {
  int blk = blockIdx.x;  // b*64 + tc   (128 blocks, 16 rows each)
  int b = blk >> 6, tc = blk & 63;
  const float* base = X + (size_t)(b * 1024 + tc * 16) * 1024;
  for (int kk = threadIdx.x; kk < 1024; kk += 256) {
    float s = 0.f;
#pragma unroll
    for (int tt = 0; tt < 16; ++tt) s += base[(size_t)tt * 1024 + kk];
    part[(size_t)blk * 1024 + kk] = s;
  }
}

__global__ __launch_bounds__(256) void xsum_reduce_kernel(
    const float* __restrict__ part, float* __restrict__ Xsum) {
  int id = blockIdx.x * 256 + threadIdx.x;  // 2048
  int b = id >> 10, k = id & 1023;
  float s = 0.f;
#pragma unroll 8
  for (int i = 0; i < 64; ++i) s += part[(size_t)(b * 64 + i) * 1024 + k];
  Xsum[id] = s;
}

__global__ __launch_bounds__(256) void vsum_gemv_kernel(
    const float* __restrict__ Xsum, const float* __restrict__ WV,
    const float* __restrict__ bV, float* __restrict__ Vsum) {
  __shared__ float xs[1024];
  int blk = blockIdx.x;  // b*16 + nc   (32 blocks)
  int b = blk >> 4;
  int n = (blk & 15) * 256 + threadIdx.x;
  for (int i = threadIdx.x; i < 1024; i += 256) xs[i] = Xsum[b * 1024 + i];
  __syncthreads();
  float a0 = 0.f, a1 = 0.f, a2 = 0.f, a3 = 0.f;
  for (int k = 0; k < 1024; k += 4) {
    a0 = fmaf(xs[k + 0], WV[(size_t)(k + 0) * 4096 + n], a0);
    a1 = fmaf(xs[k + 1], WV[(size_t)(k + 1) * 4096 + n], a1);
    a2 = fmaf(xs[k + 2], WV[(size_t)(k + 2) * 4096 + n], a2);
    a3 = fmaf(xs[k + 3], WV[(size_t)(k + 3) * 4096 + n], a3);
  }
  Vsum[b * 4096 + n] = (a0 + a1) + (a2 + a3) + 1024.0f * bV[n];
}

// ------------------------------------------------------------------
// bf16 MFMA GEMM: C[MxN] = A[MxK] @ Bt[NxK]^T + bias
// ------------------------------------------------------------------
template <bool BF16OUT>
__global__ __launch_bounds__(256) void gemm_bf16_kernel(
    const u16* __restrict__ Ab, const u16* __restrict__ Bt,
    const float* __restrict__ bias, void* __restrict__ Cv,
    int M, int N, int K)
{
  __shared__ __align__(16) u16 sA[128 * 32];
  __shared__ __align__(16) u16 sB[128 * 32];
  const int tid = threadIdx.x;
  const int lane = tid & 63;
  const int wv = tid >> 6;
  const int wm = wv >> 1, wn = wv & 1;
  const int m0 = blockIdx.y * 128, n0 = blockIdx.x * 128;

  f32x4 acc[4][4];
#pragma unroll
  for (int i = 0; i < 4; ++i)
#pragma unroll
    for (int j = 0; j < 4; ++j) acc[i][j] = (f32x4){0.f, 0.f, 0.f, 0.f};

  const int r0 = tid >> 2, kc = tid & 3;
  const u16* a_src0 = Ab + (size_t)(m0 + r0) * K + kc * 8;
  const u16* a_src1 = Ab + (size_t)(m0 + 64 + r0) * K + kc * 8;
  const u16* b_src0 = Bt + (size_t)(n0 + r0) * K + kc * 8;
  const u16* b_src1 = Bt + (size_t)(n0 + 64 + r0) * K + kc * 8;
  u16* sA0 = sA + (size_t)(wv * 64) * 8;
  u16* sA1 = sA + (size_t)(256 + wv * 64) * 8;
  u16* sB0 = sB + (size_t)(wv * 64) * 8;
  u16* sB1 = sB + (size_t)(256 + wv * 64) * 8;

  const int arow = wm * 64 + (lane & 15);
  const int brow = wn * 64 + (lane & 15);
  const int kcol = (lane >> 4) * 8;

  for (int k0 = 0; k0 < K; k0 += 32) {
    __syncthreads();
    gload16(a_src0 + k0, sA0);
    gload16(a_src1 + k0, sA1);
    gload16(b_src0 + k0, sB0);
    gload16(b_src1 + k0, sB1);
    __syncthreads();
    bf16x8 af[4], bfv[4];
#pragma unroll
    for (int mi = 0; mi < 4; ++mi)
      af[mi] = *reinterpret_cast<const bf16x8*>(&sA[(arow + mi * 16) * 32 + kcol]);
#pragma unroll
    for (int ni = 0; ni < 4; ++ni)
      bfv[ni] = *reinterpret_cast<const bf16x8*>(&sB[(brow + ni * 16) * 32 + kcol]);
#pragma unroll
    for (int mi = 0; mi < 4; ++mi)
#pragma unroll
      for (int ni = 0; ni < 4; ++ni)
        acc[mi][ni] = __builtin_amdgcn_mfma_f32_16x16x32_bf16(
            af[mi], bfv[ni], acc[mi][ni], 0, 0, 0);
  }

  const int crow = m0 + wm * 64 + (lane >> 4) * 4;
  const int ccol = n0 + wn * 64 + (lane & 15);
#pragma unroll
  for (int mi = 0; mi < 4; ++mi)
#pragma unroll
    for (int ni = 0; ni < 4; ++ni) {
      int col = ccol + ni * 16;
      float bv = bias[col];
#pragma unroll
      for (int r = 0; r < 4; ++r) {
        float val = acc[mi][ni][r] + bv;
        size_t idx = (size_t)(crow + mi * 16 + r) * N + col;
        if (BF16OUT) ((u16*)Cv)[idx] = f2bf(val);
        else ((float*)Cv)[idx] = val;
      }
    }
}

__device__ __forceinline__ float wave_sum64(float v) {
  v += __shfl_xor(v, 1, 64);
  v += __shfl_xor(v, 2, 64);
  v += __shfl_xor(v, 4, 64);
  v += __shfl_xor(v, 8, 64);
  v += __shfl_xor(v, 16, 64);
  v += __shfl_xor(v, 32, 64);
  return v;
}

// rms_norm + rope (table), in place on bf16 Qb
__global__ __launch_bounds__(256) void q_transform_kernel(
    u16* __restrict__ Qb, const float* __restrict__ ctab,
    const float* __restrict__ stab) {
  int wid  = blockIdx.x * 4 + (threadIdx.x >> 6);
  int lane = threadIdx.x & 63;
  int h  = wid & 63;
  int bt = wid >> 6;
  int t  = bt & (T_SEQ - 1);
  u16* row = Qb + (size_t)bt * 4096 + h * 64;
  float x  = bf2f(row[lane]);
  float ss = wave_sum64(x * x);
  float xn = x * rsqrtf(ss * (1.0f / 64.0f) + 1.1920929e-7f);
  int p = lane & 31;
  float x1 = __shfl(xn, 2 * p, 64);
  float x2 = __shfl(xn, 2 * p + 1, 64);
  float cs = ctab[t * 32 + p], sn = stab[t * 32 + p];
  row[lane] = f2bf((lane < 32) ? (x1 * cs - x2 * sn) : (x1 * sn + x2 * cs));
}

// rope (table) + unit-normalize, in place on bf16 Kb
__global__ __launch_bounds__(256) void k_transform_kernel(
    u16* __restrict__ Kb, const float* __restrict__ ctab,
    const float* __restrict__ stab) {
  int wid  = blockIdx.x * 4 + (threadIdx.x >> 6);
  int lane = threadIdx.x & 63;
  int hs = wid & 15;
  int bt = wid >> 4;
  int t  = bt & (T_SEQ - 1);
  u16* row = Kb + (size_t)bt * 1024 + hs * 64;
  float x = bf2f(row[lane]);
  int p = lane & 31;
  float x1 = __shfl(x, 2 * p, 64);
  float x2 = __shfl(x, 2 * p + 1, 64);
  float cs = ctab[t * 32 + p], sn = stab[t * 32 + p];
  float xr = (lane < 32) ? (x1 * cs - x2 * sn) : (x1 * sn + x2 * cs);
  float ss = wave_sum64(xr * xr);
  row[lane] = f2bf(xr * rsqrtf(ss));
}

// ------------------------------------------------------------------
// MFMA banded attention (unchanged math from R3; bf16 output store).
// ------------------------------------------------------------------
__global__ __launch_bounds__(256) void attn_mfma_kernel(
    const u16* __restrict__ Qb, const u16* __restrict__ Kb,
    const u16* __restrict__ Vb, const float* __restrict__ Vsum,
    const float* __restrict__ sink, const float* __restrict__ vnull,
    u16* __restrict__ mctxb)
{
  __shared__ __align__(16) u16 sQ[32 * 64];
  __shared__ __align__(16) u16 sK[64 * 64];
  __shared__ __align__(16) u16 sVt[64 * 64];
  __shared__ __align__(16) u16 sP[32 * 64];
  __shared__ float z_lds[2][32];

  int blk = blockIdx.x;
  blk = (blk & 7) * 128 + (blk >> 3);   // XCD-chunked remap (bijective, 1024%8==0)
  const int qt  = blk & 31;
  const int hs  = (blk >> 5) & 15;
  const int b   = blk >> 9;
  const int qt0 = qt * 32;

  const int tid  = threadIdx.x;
  const int lane = tid & 63;
  const int wv   = tid >> 6;
  const int l15  = lane & 15;
  const int l4   = lane >> 4;
  const int hq   = wv & 1;
  const int jp   = wv >> 1;
  const int dp   = wv >> 1;

  constexpr int HCFG[4] = {16, 128, 128, 512};
  constexpr int GCFG[4] = {0, 16, 0, 144};

  f32x4 macc[2];
  macc[0] = (f32x4){0.f, 0.f, 0.f, 0.f};
  macc[1] = (f32x4){0.f, 0.f, 0.f, 0.f};

#pragma unroll
  for (int br = 0; br < 4; ++br) {
    const int h = br * 16 + hs;
    const int hmax = HCFG[br], g = GCFG[br];

    {
      int c = tid;
      int qrow = c >> 3, i = c & 7;
      gload16(Qb + (size_t)(b * T_SEQ + qt0 + qrow) * 4096 + h * 64 +
                  8 * (i ^ (qrow & 7)),
              sQ + wv * 512);
    }
    __syncthreads();

    bf16x8 afQ[2];
    {
      int qrow = hq * 16 + l15;
#pragma unroll
      for (int kh = 0; kh < 2; ++kh) {
        int cs = (4 * kh + l4) ^ (qrow & 7);
        afQ[kh] = *reinterpret_cast<const bf16x8*>(&sQ[qrow * 64 + cs * 8]);
      }
    }

    f32x4 outv[2];
    outv[0] = (f32x4){0.f, 0.f, 0.f, 0.f};
    outv[1] = (f32x4){0.f, 0.f, 0.f, 0.f};
    float zacc[4] = {0.f, 0.f, 0.f, 0.f};

    int klo = qt0 - (hmax - 1); if (klo < 0) klo = 0;
    int khi = qt0 + 31 - g;     if (khi > T_SEQ - 1) khi = T_SEQ - 1;

    for (int j0 = klo; j0 <= khi; j0 += 64) {
      __syncthreads();
      {
        int c = tid;
        int jr = c >> 3, i = c & 7;
        int jc = j0 + jr; if (jc > T_SEQ - 1) jc = T_SEQ - 1;
        gload16(Kb + (size_t)(b * T_SEQ + jc) * 1024 + hs * 64 +
                    8 * (i ^ (jr & 7)),
                sK + wv * 512);
        c = tid + 256;
        jr = c >> 3; i = c & 7;
        jc = j0 + jr; if (jc > T_SEQ - 1) jc = T_SEQ - 1;
        gload16(Kb + (size_t)(b * T_SEQ + jc) * 1024 + hs * 64 +
                    8 * (i ^ (jr & 7)),
                sK + 2048 + wv * 512);
      }
      {
        int jp2 = tid & 31, dg = tid >> 5;
        int ja = j0 + 2 * jp2, jb = ja + 1;
        if (ja > T_SEQ - 1) ja = T_SEQ - 1;
        if (jb > T_SEQ - 1) jb = T_SEQ - 1;
        bf16x8 va = *reinterpret_cast<const bf16x8*>(
            &Vb[(size_t)(b * T_SEQ + ja) * 4096 + h * 64 + dg * 8]);
        bf16x8 vb = *reinterpret_cast<const bf16x8*>(
            &Vb[(size_t)(b * T_SEQ + jb) * 4096 + h * 64 + dg * 8]);
#pragma unroll
        for (int e = 0; e < 8; ++e) {
          int d = dg * 8 + e;
          u32 pack = (u32)(u16)va[e] | ((u32)(u16)vb[e] << 16);
          *reinterpret_cast<u32*>(
              (char*)sVt + d * 128 + ((4 * jp2) ^ ((d & 7) << 4))) = pack;
        }
      }
      __syncthreads();

      f32x4 sfr[2];
#pragma unroll
      for (int n = 0; n < 2; ++n) {
        int jt = jp * 2 + n;
        f32x4 acc = (f32x4){0.f, 0.f, 0.f, 0.f};
        int krow = jt * 16 + l15;
#pragma unroll
        for (int kh = 0; kh < 2; ++kh) {
          int cs = (4 * kh + l4) ^ (krow & 7);
          bf16x8 bk = *reinterpret_cast<const bf16x8*>(&sK[krow * 64 + cs * 8]);
          acc = __builtin_amdgcn_mfma_f32_16x16x32_bf16(afQ[kh], bk, acc, 0, 0, 0);
        }
        sfr[n] = acc;
      }
#pragma unroll
      for (int n = 0; n < 2; ++n) {
        int jloc = (jp * 2 + n) * 16 + l15;
        int jabs = j0 + jloc;
#pragma unroll
        for (int r = 0; r < 4; ++r) {
          int q_r = hq * 16 + l4 * 4 + r;
          int dist = (qt0 + q_r) - jabs;
          bool inband = (dist >= g) & (dist < hmax) & (jabs < T_SEQ);
          float pv = inband ? (__expf(sfr[n][r]) - 1.0f) : 0.0f;
          zacc[r] += pv;
          *reinterpret_cast<u16*>(
              (char*)sP + q_r * 128 + ((2 * jloc) ^ ((q_r & 7) << 4))) = f2bf(pv);
        }
      }
      __syncthreads();

      bf16x8 afP[2];
      {
        int prow = hq * 16 + l15;
#pragma unroll
        for (int kh = 0; kh < 2; ++kh) {
          int cs = (4 * kh + l4) ^ (prow & 7);
          afP[kh] = *reinterpret_cast<const bf16x8*>(&sP[prow * 64 + cs * 8]);
        }
      }
#pragma unroll
      for (int n = 0; n < 2; ++n) {
        int drow = (dp * 2 + n) * 16 + l15;
#pragma unroll
        for (int kh = 0; kh < 2; ++kh) {
          int cs = (4 * kh + l4) ^ (drow & 7);
          bf16x8 bv = *reinterpret_cast<const bf16x8*>(&sVt[drow * 64 + cs * 8]);
          outv[n] = __builtin_amdgcn_mfma_f32_16x16x32_bf16(afP[kh], bv, outv[n], 0, 0, 0);
        }
      }
    }

    __syncthreads();
#pragma unroll
    for (int r = 0; r < 4; ++r) {
      zacc[r] += __shfl_xor(zacc[r], 1, 64);
      zacc[r] += __shfl_xor(zacc[r], 2, 64);
      zacc[r] += __shfl_xor(zacc[r], 4, 64);
      zacc[r] += __shfl_xor(zacc[r], 8, 64);
    }
    if (l15 == 0) {
#pragma unroll
      for (int r = 0; r < 4; ++r)
        z_lds[jp][hq * 16 + l4 * 4 + r] = zacc[r];
    }
    __syncthreads();

    float es = __expf(tanhf(sink[h]));
#pragma unroll
    for (int n = 0; n < 2; ++n) {
      int d = (dp * 2 + n) * 16 + l15;
      float vs = Vsum[(b * 64 + h) * 64 + d];
      float vn = vnull[h * 64 + d];
#pragma unroll
      for (int r = 0; r < 4; ++r) {
        int q_r = hq * 16 + l4 * 4 + r;
        float z = z_lds[0][q_r] + z_lds[1][q_r];
        float invZ = 1.0f / (1024.0f + z + es);
        macc[n][r] += (outv[n][r] + vs + es * vn) * invZ;
      }
    }
  }

#pragma unroll
  for (int n = 0; n < 2; ++n) {
    int d = (dp * 2 + n) * 16 + l15;
#pragma unroll
    for (int r = 0; r < 4; ++r) {
      int q_r = hq * 16 + l4 * 4 + r;
      mctxb[(size_t)(b * T_SEQ + qt0 + q_r) * 1024 + hs * 64 + d] =
          f2bf(0.25f * macc[n][r]);
    }
  }
}

extern "C" void kernel_launch(void* const* d_in, const int* in_sizes, int n_in,
                              void* d_out, int out_size, void* d_ws, size_t ws_size,
                              hipStream_t stream) {
  (void)in_sizes; (void)n_in; (void)out_size; (void)ws_size;
  const float* X    = (const float*)d_in[0];
  const float* WQ   = (const float*)d_in[1];
  const float* bQ   = (const float*)d_in[2];
  const float* WK   = (const float*)d_in[3];
  const float* bK   = (const float*)d_in[4];
  const float* WV   = (const float*)d_in[5];
  const float* bV   = (const float*)d_in[6];
  const float* WO   = (const float*)d_in[7];
  const float* bO   = (const float*)d_in[8];
  const float* sink = (const float*)d_in[9];
  const float* vnul = (const float*)d_in[10];
  float* Y = (float*)d_out;

  char* p = (char*)d_ws;
  u16*   Xb    = (u16*)p;   p += (size_t)2048 * 1024 * 2;   //  4 MB
  u16*   WQt   = (u16*)p;   p += (size_t)4096 * 1024 * 2;   //  8 MB
  u16*   WKt   = (u16*)p;   p += (size_t)1024 * 1024 * 2;   //  2 MB
  u16*   WVt   = (u16*)p;   p += (size_t)4096 * 1024 * 2;   //  8 MB
  u16*   WOt   = (u16*)p;   p += (size_t)1024 * 1024 * 2;   //  2 MB
  u16*   Qbf   = (u16*)p;   p += (size_t)2048 * 4096 * 2;   // 16 MB
  u16*   Kbf   = (u16*)p;   p += (size_t)2048 * 1024 * 2;   //  4 MB
  u16*   Vbf   = (u16*)p;   p += (size_t)2048 * 4096 * 2;   // 16 MB
  float* Vsum  = (float*)p; p += (size_t)2 * 4096 * 4;      // 32 KB
  u16*   mctxb = (u16*)p;   p += (size_t)2048 * 1024 * 2;   //  4 MB
  float* part  = (float*)p; p += (size_t)128 * 1024 * 4;    // 512 KB
  float* Xsum  = (float*)p; p += (size_t)2 * 1024 * 4;      //  8 KB
  float* ctab  = (float*)p; p += (size_t)1024 * 32 * 4;     // 128 KB
  float* stab  = (float*)p; p += (size_t)1024 * 32 * 4;     // 128 KB

  dim3 blk(256);
  rope_table_kernel<<<128, blk, 0, stream>>>(ctab, stab);
  cvt_bf16_kernel<<<1024, blk, 0, stream>>>(X, Xb, 262144);
  transpose_cvt_kernel<<<dim3(128, 32), blk, 0, stream>>>(WQ, WQt, 4096, 1024);
  transpose_cvt_kernel<<<dim3(32, 32),  blk, 0, stream>>>(WK, WKt, 1024, 1024);
  transpose_cvt_kernel<<<dim3(128, 32), blk, 0, stream>>>(WV, WVt, 4096, 1024);
  transpose_cvt_kernel<<<dim3(32, 32),  blk, 0, stream>>>(WO, WOt, 1024, 1024);

  xsum_part_kernel<<<128, blk, 0, stream>>>(X, part);
  xsum_reduce_kernel<<<8, blk, 0, stream>>>(part, Xsum);
  vsum_gemv_kernel<<<32, blk, 0, stream>>>(Xsum, WV, bV, Vsum);

  gemm_bf16_kernel<true><<<dim3(32, 16), blk, 0, stream>>>(Xb, WQt, bQ, Qbf, 2048, 4096, 1024);
  gemm_bf16_kernel<true><<<dim3(8, 16),  blk, 0, stream>>>(Xb, WKt, bK, Kbf, 2048, 1024, 1024);
  gemm_bf16_kernel<true><<<dim3(32, 16), blk, 0, stream>>>(Xb, WVt, bV, Vbf, 2048, 4096, 1024);

  q_transform_kernel<<<(2048 * 64) / 4, blk, 0, stream>>>(Qbf, ctab, stab);
  k_transform_kernel<<<(2048 * 16) / 4, blk, 0, stream>>>(Kbf, ctab, stab);

  attn_mfma_kernel<<<1024, blk, 0, stream>>>(Qbf, Kbf, Vbf, Vsum, sink, vnul, mctxb);

  gemm_bf16_kernel<false><<<dim3(8, 16), blk, 0, stream>>>(mctxb, WOt, bO, Y, 2048, 1024, 1024);
}

// Round 5
// 171.351 us; speedup vs baseline: 5.7767x; 1.4056x over previous
//
#include <hip/hip_runtime.h>
#include <hip/hip_bf16.h>
#include <math.h>

#define T_SEQ 1024
#define LOG2_10000 13.287712379549449f

typedef unsigned short u16;
typedef unsigned int u32;
typedef __attribute__((ext_vector_type(8))) short bf16x8;
typedef __attribute__((ext_vector_type(4))) float f32x4;

__device__ __forceinline__ void gload16(const u16* g, const u16* s) {
  __builtin_amdgcn_global_load_lds(
      (const __attribute__((address_space(1))) void*)g,
      (__attribute__((address_space(3))) void*)s, 16, 0, 0);
}

__device__ __forceinline__ u16 f2bf(float x) {
  __hip_bfloat16 h = __float2bfloat16(x);
  return *reinterpret_cast<u16*>(&h);
}
__device__ __forceinline__ float bf2f(u16 x) {
  __hip_bfloat16 h = *reinterpret_cast<__hip_bfloat16*>(&x);
  return __bfloat162float(h);
}

__device__ __forceinline__ float wave_sum64(float v) {
  v += __shfl_xor(v, 1, 64);
  v += __shfl_xor(v, 2, 64);
  v += __shfl_xor(v, 4, 64);
  v += __shfl_xor(v, 8, 64);
  v += __shfl_xor(v, 16, 64);
  v += __shfl_xor(v, 32, 64);
  return v;
}

// ------------------------------------------------------------------
// transpose helper: W[K=1024][N] fp32 -> Wt[N][1024] bf16, one 32x32 tile
// ------------------------------------------------------------------
__device__ __forceinline__ void transpose_step(
    const float* __restrict__ W, u16* __restrict__ Wt, int N, int nbx,
    int local, int t, float (*tile)[33]) {
  int bx = local % nbx, by = local / nbx;
  int n0 = bx * 32, k0 = by * 32;
  int r = t >> 3, c4 = (t & 7) * 4;
  float4 v = *reinterpret_cast<const float4*>(&W[(size_t)(k0 + r) * N + n0 + c4]);
  tile[r][c4 + 0] = v.x;
  tile[r][c4 + 1] = v.y;
  tile[r][c4 + 2] = v.z;
  tile[r][c4 + 3] = v.w;
  __syncthreads();
  u16 o[4];
#pragma unroll
  for (int i = 0; i < 4; ++i) o[i] = f2bf(tile[c4 + i][r]);
  *reinterpret_cast<uint2*>(&Wt[(size_t)(n0 + r) * 1024 + k0 + c4]) =
      *reinterpret_cast<const uint2*>(o);
}

// ------------------------------------------------------------------
// fused prep: rope tables | X cvt | WQ,WV -> WQVt | WK -> WKt | WO -> WOt
//             | bias concat [bQ;bV]
// ------------------------------------------------------------------
__global__ __launch_bounds__(256) void prep_kernel(
    const float* __restrict__ X, const float* __restrict__ WQ,
    const float* __restrict__ WK, const float* __restrict__ WV,
    const float* __restrict__ WO, const float* __restrict__ bQ,
    const float* __restrict__ bV, u16* __restrict__ Xb,
    u16* __restrict__ WQVt, u16* __restrict__ WKt, u16* __restrict__ WOt,
    float* __restrict__ bQV, float* __restrict__ ctab, float* __restrict__ stab)
{
  __shared__ float tile[32][33];
  const int blk = blockIdx.x, t = threadIdx.x;
  if (blk < 128) {                       // rope tables (32768)
    int id = blk * 256 + t;
    int tt = id >> 5, p = id & 31;
    float invf = exp2f(-LOG2_10000 * (float)(2 * p) * (1.0f / 64.0f));
    float ang = (float)tt * invf;
    float sn, cs;
    sincosf(ang, &sn, &cs);
    ctab[id] = cs;
    stab[id] = sn;
  } else if (blk < 1152) {               // X fp32 -> bf16 (262144 x8)
    int i = (blk - 128) * 256 + t;
    float4 a = reinterpret_cast<const float4*>(X)[2 * i];
    float4 b = reinterpret_cast<const float4*>(X)[2 * i + 1];
    u16 o[8] = {f2bf(a.x), f2bf(a.y), f2bf(a.z), f2bf(a.w),
                f2bf(b.x), f2bf(b.y), f2bf(b.z), f2bf(b.w)};
    reinterpret_cast<uint4*>(Xb)[i] = *reinterpret_cast<const uint4*>(o);
  } else if (blk < 5248) {
    transpose_step(WQ, WQVt, 4096, 128, blk - 1152, t, tile);
  } else if (blk < 9344) {
    transpose_step(WV, WQVt + (size_t)4096 * 1024, 4096, 128, blk - 5248, t, tile);
  } else if (blk < 10368) {
    transpose_step(WK, WKt, 1024, 32, blk - 9344, t, tile);
  } else if (blk < 11392) {
    transpose_step(WO, WOt, 1024, 32, blk - 10368, t, tile);
  } else {                               // bias concat (8192)
    int id = (blk - 11392) * 256 + t;
    bQV[id] = (id < 4096) ? bQ[id] : bV[id - 4096];
  }
}

// ------------------------------------------------------------------
// Vsum[b][n] = (sum_t X[b,t,:]) @ WV[:,n] + 1024*bV[n]   (all fp32 exact)
// ------------------------------------------------------------------
__global__ __launch_bounds__(256) void xsum_part_kernel(
    const float* __restrict__ X, float* __restrict__ part) {
  int blk = blockIdx.x;  // b*64 + tc
  int b = blk >> 6, tc = blk & 63;
  const float* base = X + (size_t)(b * 1024 + tc * 16) * 1024;
  for (int kk = threadIdx.x; kk < 1024; kk += 256) {
    float s = 0.f;
#pragma unroll
    for (int tt = 0; tt < 16; ++tt) s += base[(size_t)tt * 1024 + kk];
    part[(size_t)blk * 1024 + kk] = s;
  }
}

__global__ __launch_bounds__(256) void xsum_reduce_kernel(
    const float* __restrict__ part, float* __restrict__ Xsum) {
  int id = blockIdx.x * 256 + threadIdx.x;  // 2048
  int b = id >> 10, k = id & 1023;
  float s = 0.f;
#pragma unroll 8
  for (int i = 0; i < 64; ++i) s += part[(size_t)(b * 64 + i) * 1024 + k];
  Xsum[id] = s;
}

__global__ __launch_bounds__(256) void vgemv_part_kernel(
    const float* __restrict__ Xsum, const float* __restrict__ WV,
    float* __restrict__ part2) {
  __shared__ float xs0[128], xs1[128];
  int blk = blockIdx.x;  // nc(16) x ks(8)
  int nc = blk & 15, ks = blk >> 4;
  int n = nc * 256 + threadIdx.x;
  int k0 = ks * 128;
  if (threadIdx.x < 128) xs0[threadIdx.x] = Xsum[k0 + threadIdx.x];
  else xs1[threadIdx.x - 128] = Xsum[1024 + k0 + threadIdx.x - 128];
  __syncthreads();
  float a0 = 0.f, a1 = 0.f;
  for (int k = 0; k < 128; ++k) {
    float w = WV[(size_t)(k0 + k) * 4096 + n];
    a0 = fmaf(xs0[k], w, a0);
    a1 = fmaf(xs1[k], w, a1);
  }
  part2[(size_t)(ks * 2 + 0) * 4096 + n] = a0;
  part2[(size_t)(ks * 2 + 1) * 4096 + n] = a1;
}

__global__ __launch_bounds__(256) void vgemv_reduce_kernel(
    const float* __restrict__ part2, const float* __restrict__ bV,
    float* __restrict__ Vsum) {
  int id = blockIdx.x * 256 + threadIdx.x;  // 8192
  int b = id >> 12, n = id & 4095;
  float s = 1024.0f * bV[n];
#pragma unroll
  for (int ks = 0; ks < 8; ++ks) s += part2[(size_t)(ks * 2 + b) * 4096 + n];
  Vsum[id] = s;
}

// ------------------------------------------------------------------
// bf16 MFMA GEMM (m97 structure): C[MxN] = A @ Bt^T + bias, 128x128 tile
// ------------------------------------------------------------------
template <bool BF16OUT>
__global__ __launch_bounds__(256) void gemm_bf16_kernel(
    const u16* __restrict__ Ab, const u16* __restrict__ Bt,
    const float* __restrict__ bias, void* __restrict__ Cv,
    int M, int N, int K)
{
  __shared__ __align__(16) u16 sA[128 * 32];
  __shared__ __align__(16) u16 sB[128 * 32];
  const int tid = threadIdx.x;
  const int lane = tid & 63;
  const int wv = tid >> 6;
  const int wm = wv >> 1, wn = wv & 1;
  const int m0 = blockIdx.y * 128, n0 = blockIdx.x * 128;

  f32x4 acc[4][4];
#pragma unroll
  for (int i = 0; i < 4; ++i)
#pragma unroll
    for (int j = 0; j < 4; ++j) acc[i][j] = (f32x4){0.f, 0.f, 0.f, 0.f};

  const int r0 = tid >> 2, kc = tid & 3;
  const u16* a_src0 = Ab + (size_t)(m0 + r0) * K + kc * 8;
  const u16* a_src1 = Ab + (size_t)(m0 + 64 + r0) * K + kc * 8;
  const u16* b_src0 = Bt + (size_t)(n0 + r0) * K + kc * 8;
  const u16* b_src1 = Bt + (size_t)(n0 + 64 + r0) * K + kc * 8;
  u16* sA0 = sA + (size_t)(wv * 64) * 8;
  u16* sA1 = sA + (size_t)(256 + wv * 64) * 8;
  u16* sB0 = sB + (size_t)(wv * 64) * 8;
  u16* sB1 = sB + (size_t)(256 + wv * 64) * 8;

  const int arow = wm * 64 + (lane & 15);
  const int brow = wn * 64 + (lane & 15);
  const int kcol = (lane >> 4) * 8;

  for (int k0 = 0; k0 < K; k0 += 32) {
    __syncthreads();
    gload16(a_src0 + k0, sA0);
    gload16(a_src1 + k0, sA1);
    gload16(b_src0 + k0, sB0);
    gload16(b_src1 + k0, sB1);
    __syncthreads();
    bf16x8 af[4], bfv[4];
#pragma unroll
    for (int mi = 0; mi < 4; ++mi)
      af[mi] = *reinterpret_cast<const bf16x8*>(&sA[(arow + mi * 16) * 32 + kcol]);
#pragma unroll
    for (int ni = 0; ni < 4; ++ni)
      bfv[ni] = *reinterpret_cast<const bf16x8*>(&sB[(brow + ni * 16) * 32 + kcol]);
#pragma unroll
    for (int mi = 0; mi < 4; ++mi)
#pragma unroll
      for (int ni = 0; ni < 4; ++ni)
        acc[mi][ni] = __builtin_amdgcn_mfma_f32_16x16x32_bf16(
            af[mi], bfv[ni], acc[mi][ni], 0, 0, 0);
  }

  const int crow = m0 + wm * 64 + (lane >> 4) * 4;
  const int ccol = n0 + wn * 64 + (lane & 15);
#pragma unroll
  for (int mi = 0; mi < 4; ++mi)
#pragma unroll
    for (int ni = 0; ni < 4; ++ni) {
      int col = ccol + ni * 16;
      float bv = bias[col];
#pragma unroll
      for (int r = 0; r < 4; ++r) {
        float val = acc[mi][ni][r] + bv;
        size_t idx = (size_t)(crow + mi * 16 + r) * N + col;
        if (BF16OUT) ((u16*)Cv)[idx] = f2bf(val);
        else ((float*)Cv)[idx] = val;
      }
    }
}

// ------------------------------------------------------------------
// 64x64-tile bf16 MFMA GEMM for small-N GEMMs (full-chip grids)
// ------------------------------------------------------------------
template <bool BF16OUT>
__global__ __launch_bounds__(256) void gemm64_kernel(
    const u16* __restrict__ Ab, const u16* __restrict__ Bt,
    const float* __restrict__ bias, void* __restrict__ Cv,
    int M, int N, int K)
{
  __shared__ __align__(16) u16 sA[64 * 32];
  __shared__ __align__(16) u16 sB[64 * 32];
  const int tid = threadIdx.x;
  const int lane = tid & 63;
  const int wv = tid >> 6;
  const int wm = wv >> 1, wn = wv & 1;
  const int l15 = lane & 15, l4 = lane >> 4;
  const int m0 = blockIdx.y * 64, n0 = blockIdx.x * 64;

  f32x4 acc[2][2];
#pragma unroll
  for (int i = 0; i < 2; ++i)
#pragma unroll
    for (int j = 0; j < 2; ++j) acc[i][j] = (f32x4){0.f, 0.f, 0.f, 0.f};

  const int r0 = tid >> 2, kc = tid & 3;
  const u16* a_src = Ab + (size_t)(m0 + r0) * K + kc * 8;
  const u16* b_src = Bt + (size_t)(n0 + r0) * K + kc * 8;
  u16* dA = sA + (size_t)wv * 512;
  u16* dB = sB + (size_t)wv * 512;
  const int kcol = l4 * 8;

  for (int k0 = 0; k0 < K; k0 += 32) {
    __syncthreads();
    gload16(a_src + k0, dA);
    gload16(b_src + k0, dB);
    __syncthreads();
    bf16x8 af[2], bfv[2];
#pragma unroll
    for (int mi = 0; mi < 2; ++mi)
      af[mi] = *reinterpret_cast<const bf16x8*>(&sA[(wm * 32 + mi * 16 + l15) * 32 + kcol]);
#pragma unroll
    for (int ni = 0; ni < 2; ++ni)
      bfv[ni] = *reinterpret_cast<const bf16x8*>(&sB[(wn * 32 + ni * 16 + l15) * 32 + kcol]);
#pragma unroll
    for (int mi = 0; mi < 2; ++mi)
#pragma unroll
      for (int ni = 0; ni < 2; ++ni)
        acc[mi][ni] = __builtin_amdgcn_mfma_f32_16x16x32_bf16(
            af[mi], bfv[ni], acc[mi][ni], 0, 0, 0);
  }

#pragma unroll
  for (int mi = 0; mi < 2; ++mi)
#pragma unroll
    for (int ni = 0; ni < 2; ++ni) {
      int col = n0 + wn * 32 + ni * 16 + l15;
      float bv = bias[col];
#pragma unroll
      for (int r = 0; r < 4; ++r) {
        int row = m0 + wm * 32 + mi * 16 + l4 * 4 + r;
        float val = acc[mi][ni][r] + bv;
        size_t idx = (size_t)row * N + col;
        if (BF16OUT) ((u16*)Cv)[idx] = f2bf(val);
        else ((float*)Cv)[idx] = val;
      }
    }
}

// ------------------------------------------------------------------
// fused q (rms+rope, in QVbf cols 0..4095) and k (rope+unitnorm) transform
// ------------------------------------------------------------------
__global__ __launch_bounds__(256) void qk_transform_kernel(
    u16* __restrict__ QVbf, u16* __restrict__ Kbf,
    const float* __restrict__ ctab, const float* __restrict__ stab)
{
  int wid = blockIdx.x * 4 + (threadIdx.x >> 6);
  int lane = threadIdx.x & 63;
  int p = lane & 31;
  if (wid < 131072) {
    int h = wid & 63, bt = wid >> 6, t = bt & 1023;
    u16* row = QVbf + (size_t)bt * 8192 + h * 64;
    float x = bf2f(row[lane]);
    float ss = wave_sum64(x * x);
    float xn = x * rsqrtf(ss * (1.0f / 64.0f) + 1.1920929e-7f);
    float x1 = __shfl(xn, 2 * p, 64);
    float x2 = __shfl(xn, 2 * p + 1, 64);
    float cs = ctab[t * 32 + p], sn = stab[t * 32 + p];
    row[lane] = f2bf((lane < 32) ? (x1 * cs - x2 * sn) : (x1 * sn + x2 * cs));
  } else {
    int w2 = wid - 131072;
    int hsL = w2 & 15, bt = w2 >> 4, t = bt & 1023;
    u16* row = Kbf + (size_t)bt * 1024 + hsL * 64;
    float x = bf2f(row[lane]);
    float x1 = __shfl(x, 2 * p, 64);
    float x2 = __shfl(x, 2 * p + 1, 64);
    float cs = ctab[t * 32 + p], sn = stab[t * 32 + p];
    float xr = (lane < 32) ? (x1 * cs - x2 * sn) : (x1 * sn + x2 * cs);
    float ss = wave_sum64(xr * xr);
    row[lane] = f2bf(xr * rsqrtf(ss));
  }
}

// ------------------------------------------------------------------
// MFMA banded attention, QBLK=64, 2-phase double-buffered K/V pipeline.
//   num = Vsum + sum_band (e^s - 1) v + es*vnull ; Z = 1024 + sum + es
// Wave wv owns q rows [wv*16, wv*16+16); one raw barrier per chunk.
// ------------------------------------------------------------------
__global__ __launch_bounds__(256) void attn_mfma_kernel(
    const u16* __restrict__ Qv, const u16* __restrict__ Kb,
    const float* __restrict__ Vsum, const float* __restrict__ sink,
    const float* __restrict__ vnull, u16* __restrict__ mctxb)
{
  __shared__ __align__(16) u16 sQ[64 * 64];
  __shared__ __align__(16) u16 sK[2][64 * 64];
  __shared__ __align__(16) u16 sVt[2][64 * 64];
  __shared__ __align__(16) u16 sP[64 * 64];

  int blk = blockIdx.x;
  blk = (blk & 7) * 64 + (blk >> 3);   // XCD-chunked (512 % 8 == 0, bijective)
  const int qt  = blk & 15;
  const int hs  = (blk >> 4) & 15;
  const int b   = blk >> 8;
  const int qt0 = qt * 64;

  const int tid  = threadIdx.x;
  const int lane = tid & 63;
  const int wv   = tid >> 6;
  const int l15  = lane & 15;
  const int l4   = lane >> 4;
  const int qr0  = tid >> 3, qi0 = tid & 7;  // staging row/chunk decode
  const int qr1  = qr0 + 32;
  const int vjp  = tid & 31, vdg = tid >> 5;
  const int qrow = wv * 16 + l15;

  constexpr int HCFG[4] = {16, 128, 128, 512};
  constexpr int GCFG[4] = {0, 16, 0, 144};

  f32x4 macc[4];
#pragma unroll
  for (int i = 0; i < 4; ++i) macc[i] = (f32x4){0.f, 0.f, 0.f, 0.f};

#pragma unroll 1
  for (int br = 0; br < 4; ++br) {
    const int h = br * 16 + hs;
    const int hmax = HCFG[br], g = GCFG[br];
    int klo = qt0 - (hmax - 1); if (klo < 0) klo = 0;
    int khi = qt0 + 63 - g;     if (khi > 1023) khi = 1023;
    const int nc = (khi >= klo) ? ((khi - klo) / 64 + 1) : 0;

    // ---- prologue: stage Q, K[0]; V reg loads for chunk 0 ----
    gload16(Qv + (size_t)(b * 1024 + qt0 + qr0) * 8192 + h * 64 + 8 * (qi0 ^ (qr0 & 7)),
            sQ + (size_t)wv * 512);
    gload16(Qv + (size_t)(b * 1024 + qt0 + qr1) * 8192 + h * 64 + 8 * (qi0 ^ (qr1 & 7)),
            sQ + 2048 + (size_t)wv * 512);
    bf16x8 va, vb;
    if (nc > 0) {
      int ja0 = klo + qr0; if (ja0 > 1023) ja0 = 1023;
      int ja1 = klo + qr1; if (ja1 > 1023) ja1 = 1023;
      gload16(Kb + (size_t)(b * 1024 + ja0) * 1024 + hs * 64 + 8 * (qi0 ^ (qr0 & 7)),
              sK[0] + (size_t)wv * 512);
      gload16(Kb + (size_t)(b * 1024 + ja1) * 1024 + hs * 64 + 8 * (qi0 ^ (qr1 & 7)),
              sK[0] + 2048 + (size_t)wv * 512);
      int jva = klo + 2 * vjp, jvb = jva + 1;
      if (jva > 1023) jva = 1023;
      if (jvb > 1023) jvb = 1023;
      va = *reinterpret_cast<const bf16x8*>(
          &Qv[(size_t)(b * 1024 + jva) * 8192 + 4096 + h * 64 + vdg * 8]);
      vb = *reinterpret_cast<const bf16x8*>(
          &Qv[(size_t)(b * 1024 + jvb) * 8192 + 4096 + h * 64 + vdg * 8]);
    }
    asm volatile("s_waitcnt vmcnt(0)" ::: "memory");
    __builtin_amdgcn_sched_barrier(0);
    if (nc > 0) {
#pragma unroll
      for (int e = 0; e < 8; ++e) {
        int d = vdg * 8 + e;
        u32 pack = (u32)(u16)va[e] | ((u32)(u16)vb[e] << 16);
        *reinterpret_cast<u32*>(
            (char*)sVt[0] + d * 128 + ((4 * vjp) ^ ((d & 7) << 4))) = pack;
      }
    }
    asm volatile("s_waitcnt lgkmcnt(0)" ::: "memory");
    __builtin_amdgcn_sched_barrier(0);
    __builtin_amdgcn_s_barrier();

    bf16x8 afQ[2];
#pragma unroll
    for (int kh = 0; kh < 2; ++kh) {
      int cs = (4 * kh + l4) ^ (l15 & 7);
      afQ[kh] = *reinterpret_cast<const bf16x8*>(&sQ[qrow * 64 + cs * 8]);
    }

    f32x4 outv[4];
#pragma unroll
    for (int i = 0; i < 4; ++i) outv[i] = (f32x4){0.f, 0.f, 0.f, 0.f};
    float zacc[4] = {0.f, 0.f, 0.f, 0.f};

    int buf = 0;
#pragma unroll 1
    for (int c = 0; c < nc; ++c) {
      const int j0 = klo + c * 64;
      const bool nxt = (c + 1 < nc);
      if (nxt) {  // issue next chunk's K gloads + V reg loads (async)
        int j0n = j0 + 64;
        int ja0 = j0n + qr0; if (ja0 > 1023) ja0 = 1023;
        int ja1 = j0n + qr1; if (ja1 > 1023) ja1 = 1023;
        gload16(Kb + (size_t)(b * 1024 + ja0) * 1024 + hs * 64 + 8 * (qi0 ^ (qr0 & 7)),
                sK[buf ^ 1] + (size_t)wv * 512);
        gload16(Kb + (size_t)(b * 1024 + ja1) * 1024 + hs * 64 + 8 * (qi0 ^ (qr1 & 7)),
                sK[buf ^ 1] + 2048 + (size_t)wv * 512);
        int jva = j0n + 2 * vjp, jvb = jva + 1;
        if (jva > 1023) jva = 1023;
        if (jvb > 1023) jvb = 1023;
        va = *reinterpret_cast<const bf16x8*>(
            &Qv[(size_t)(b * 1024 + jva) * 8192 + 4096 + h * 64 + vdg * 8]);
        vb = *reinterpret_cast<const bf16x8*>(
            &Qv[(size_t)(b * 1024 + jvb) * 8192 + 4096 + h * 64 + vdg * 8]);
      }
      // ---- QK^T: wave computes S[16 q][64 j] ----
      f32x4 sfr[4];
#pragma unroll
      for (int jt = 0; jt < 4; ++jt) {
        int krow = jt * 16 + l15;
        f32x4 acc = (f32x4){0.f, 0.f, 0.f, 0.f};
#pragma unroll
        for (int kh = 0; kh < 2; ++kh) {
          int cs = (4 * kh + l4) ^ (l15 & 7);
          bf16x8 bk = *reinterpret_cast<const bf16x8*>(&sK[buf][krow * 64 + cs * 8]);
          acc = __builtin_amdgcn_mfma_f32_16x16x32_bf16(afQ[kh], bk, acc, 0, 0, 0);
        }
        sfr[jt] = acc;
      }
      // ---- P = inband ? e^s - 1 : 0 ; z ; sP (own-wave rows) ----
#pragma unroll
      for (int jt = 0; jt < 4; ++jt) {
        int jloc = jt * 16 + l15;
        int jabs = j0 + jloc;
#pragma unroll
        for (int r = 0; r < 4; ++r) {
          int q_r = wv * 16 + l4 * 4 + r;
          int dist = (qt0 + q_r) - jabs;
          bool inband = (dist >= g) & (dist < hmax) & (jabs < 1024);
          float pv = inband ? (__expf(sfr[jt][r]) - 1.0f) : 0.0f;
          zacc[r] += pv;
          *reinterpret_cast<u16*>(
              (char*)sP + q_r * 128 + ((2 * jloc) ^ ((q_r & 7) << 4))) = f2bf(pv);
        }
      }
      // own-wave sP visibility (each wave reads only rows it wrote)
      asm volatile("s_waitcnt lgkmcnt(0)" ::: "memory");
      __builtin_amdgcn_sched_barrier(0);
      // ---- PV: out[16 q][64 d] += P @ V^T ----
      bf16x8 afP[2];
#pragma unroll
      for (int kh = 0; kh < 2; ++kh) {
        int cs = (4 * kh + l4) ^ (l15 & 7);
        afP[kh] = *reinterpret_cast<const bf16x8*>(&sP[qrow * 64 + cs * 8]);
      }
#pragma unroll
      for (int dt = 0; dt < 4; ++dt) {
        int drow = dt * 16 + l15;
#pragma unroll
        for (int kh = 0; kh < 2; ++kh) {
          int cs = (4 * kh + l4) ^ (l15 & 7);
          bf16x8 bv = *reinterpret_cast<const bf16x8*>(&sVt[buf][drow * 64 + cs * 8]);
          outv[dt] = __builtin_amdgcn_mfma_f32_16x16x32_bf16(afP[kh], bv, outv[dt], 0, 0, 0);
        }
      }
      if (nxt) {  // write next chunk's V^T into other buffer
#pragma unroll
        for (int e = 0; e < 8; ++e) {
          int d = vdg * 8 + e;
          u32 pack = (u32)(u16)va[e] | ((u32)(u16)vb[e] << 16);
          *reinterpret_cast<u32*>(
              (char*)sVt[buf ^ 1] + d * 128 + ((4 * vjp) ^ ((d & 7) << 4))) = pack;
        }
      }
      // end-of-chunk: K gloads landed, V writes visible, all reads retired
      asm volatile("s_waitcnt vmcnt(0) lgkmcnt(0)" ::: "memory");
      __builtin_amdgcn_sched_barrier(0);
      __builtin_amdgcn_s_barrier();
      buf ^= 1;
    }

    // ---- branch epilogue: wave-local z reduce, normalize, accumulate ----
#pragma unroll
    for (int r = 0; r < 4; ++r) {
      zacc[r] += __shfl_xor(zacc[r], 1, 64);
      zacc[r] += __shfl_xor(zacc[r], 2, 64);
      zacc[r] += __shfl_xor(zacc[r], 4, 64);
      zacc[r] += __shfl_xor(zacc[r], 8, 64);
    }
    float es = __expf(tanhf(sink[h]));
#pragma unroll
    for (int dt = 0; dt < 4; ++dt) {
      int d = dt * 16 + l15;
      float vs = Vsum[(size_t)b * 4096 + h * 64 + d];
      float vn = vnull[h * 64 + d];
#pragma unroll
      for (int r = 0; r < 4; ++r) {
        float invZ = 1.0f / (1024.0f + zacc[r] + es);
        macc[dt][r] += (outv[dt][r] + vs + es * vn) * invZ;
      }
    }
  }

#pragma unroll
  for (int dt = 0; dt < 4; ++dt) {
#pragma unroll
    for (int r = 0; r < 4; ++r) {
      int q_r = wv * 16 + l4 * 4 + r;
      mctxb[(size_t)(b * 1024 + qt0 + q_r) * 1024 + hs * 64 + dt * 16 + l15] =
          f2bf(0.25f * macc[dt][r]);
    }
  }
}

extern "C" void kernel_launch(void* const* d_in, const int* in_sizes, int n_in,
                              void* d_out, int out_size, void* d_ws, size_t ws_size,
                              hipStream_t stream) {
  (void)in_sizes; (void)n_in; (void)out_size; (void)ws_size;
  const float* X    = (const float*)d_in[0];
  const float* WQ   = (const float*)d_in[1];
  const float* bQ   = (const float*)d_in[2];
  const float* WK   = (const float*)d_in[3];
  const float* bK   = (const float*)d_in[4];
  const float* WV   = (const float*)d_in[5];
  const float* bV   = (const float*)d_in[6];
  const float* WO   = (const float*)d_in[7];
  const float* bO   = (const float*)d_in[8];
  const float* sink = (const float*)d_in[9];
  const float* vnul = (const float*)d_in[10];
  float* Y = (float*)d_out;

  char* p = (char*)d_ws;
  u16*   Xb    = (u16*)p;   p += (size_t)2048 * 1024 * 2;   //  4 MB
  u16*   WQVt  = (u16*)p;   p += (size_t)8192 * 1024 * 2;   // 16 MB
  u16*   WKt   = (u16*)p;   p += (size_t)1024 * 1024 * 2;   //  2 MB
  u16*   WOt   = (u16*)p;   p += (size_t)1024 * 1024 * 2;   //  2 MB
  u16*   QVbf  = (u16*)p;   p += (size_t)2048 * 8192 * 2;   // 32 MB
  u16*   Kbf   = (u16*)p;   p += (size_t)2048 * 1024 * 2;   //  4 MB
  u16*   mctxb = (u16*)p;   p += (size_t)2048 * 1024 * 2;   //  4 MB
  float* Vsum  = (float*)p; p += (size_t)2 * 4096 * 4;      // 32 KB
  float* part  = (float*)p; p += (size_t)128 * 1024 * 4;    // 512 KB
  float* Xsum  = (float*)p; p += (size_t)2 * 1024 * 4;      //   8 KB
  float* part2 = (float*)p; p += (size_t)16 * 4096 * 4;     // 256 KB
  float* bQV   = (float*)p; p += (size_t)8192 * 4;          //  32 KB
  float* ctab  = (float*)p; p += (size_t)32768 * 4;         // 128 KB
  float* stab  = (float*)p; p += (size_t)32768 * 4;         // 128 KB

  dim3 blk(256);
  prep_kernel<<<11424, blk, 0, stream>>>(X, WQ, WK, WV, WO, bQ, bV,
                                         Xb, WQVt, WKt, WOt, bQV, ctab, stab);
  xsum_part_kernel<<<128, blk, 0, stream>>>(X, part);
  xsum_reduce_kernel<<<8, blk, 0, stream>>>(part, Xsum);
  vgemv_part_kernel<<<128, blk, 0, stream>>>(Xsum, WV, part2);
  vgemv_reduce_kernel<<<32, blk, 0, stream>>>(part2, bV, Vsum);

  gemm_bf16_kernel<true><<<dim3(64, 16), blk, 0, stream>>>(Xb, WQVt, bQV, QVbf, 2048, 8192, 1024);
  gemm64_kernel<true><<<dim3(16, 32), blk, 0, stream>>>(Xb, WKt, bK, Kbf, 2048, 1024, 1024);

  qk_transform_kernel<<<40960, blk, 0, stream>>>(QVbf, Kbf, ctab, stab);

  attn_mfma_kernel<<<512, blk, 0, stream>>>(QVbf, Kbf, Vsum, sink, vnul, mctxb);

  gemm64_kernel<false><<<dim3(16, 32), blk, 0, stream>>>(mctxb, WOt, bO, Y, 2048, 1024, 1024);
}